// Round 3
// baseline (4893.370 us; speedup 1.0000x reference)
//
#include <hip/hip_runtime.h>
#include <hip/hip_bf16.h>

// Problem dims
#define BB 16
#define SS 512
#define IN_ 128
#define DD 512
#define HH 512
#define DA 30
#define RR 10
#define G3 1536   // 3*H

// ---- ws layout (bytes) ----
constexpr size_t OFF_H    = 0;              // h double-buffer [2][16][512] f32 : 65,536
constexpr size_t OFF_FL   = 65536;          // sync counters: 4,096
constexpr size_t OFF_DF   = 69632;          // dtype flag: 256
constexpr size_t OFF_CX   = 69888;          // canonical fp32 inputs:
constexpr size_t OFF_CW0  = OFF_CX   + 4194304;
constexpr size_t OFF_CB0  = OFF_CW0  + 262144;
constexpr size_t OFF_CW1  = OFF_CB0  + 2048;
constexpr size_t OFF_CB1  = OFF_CW1  + 61440;
constexpr size_t OFF_CW2  = OFF_CB1  + 256;
constexpr size_t OFF_CB2  = OFF_CW2  + 2048;
constexpr size_t OFF_CWIH = OFF_CB2  + 256;
constexpr size_t OFF_CWHH = OFF_CWIH + 3145728;
constexpr size_t OFF_CBI  = OFF_CWHH + 3145728;
constexpr size_t OFF_CBH  = OFF_CBI  + 6144;
constexpr size_t OFF_WT   = OFF_CBH  + 6144;          // W_hh^T bf16 [1536][512]
constexpr size_t OFF_MM   = OFF_WT   + 1572864;       // M bf16 [8192][512]
constexpr size_t OFF_BIG  = OFF_MM   + 8388608;
constexpr size_t OFF_M    = OFF_BIG;                  // m bf16 [8192][512]
constexpr size_t OFF_E    = OFF_BIG  + 8388608;       // e f32 [8192][10]
constexpr size_t OFF_INV  = OFF_E    + 327680;        // inv f32
constexpr size_t OFF_GI   = OFF_BIG;                  // gi aliases m/e/inv (dead after k_attn)
constexpr size_t NEED_GI32 = OFF_BIG + 50331648;      // gi fp32 total ~71.2 MB

__device__ __forceinline__ float bflo(unsigned int u) { return __uint_as_float(u << 16); }
__device__ __forceinline__ float bfhi(unsigned int u) { return __uint_as_float(u & 0xffff0000u); }
__device__ __forceinline__ float bf1(unsigned short u) { return __uint_as_float(((unsigned int)u) << 16); }

__device__ __forceinline__ float ldgi(const float* p) { return *p; }
__device__ __forceinline__ float ldgi(const __hip_bfloat16* p) { return __bfloat162float(*p); }
__device__ __forceinline__ void stgi(float* p, float v) { *p = v; }
__device__ __forceinline__ void stgi(__hip_bfloat16* p, float v) { *p = __float2bfloat16(v); }

// ---------------- K0a: detect input dtype. fp32 reinterpreted as bf16 -> ~45% huge/NaN. ----
__global__ __launch_bounds__(1024) void k_detect(const unsigned short* __restrict__ xs,
                                                 int* __restrict__ dflag) {
  const int tid = threadIdx.x;
  int bad = 0;
  for (int i = tid; i < 65536; i += 1024) {
    const float v = bf1(xs[i]);
    if (!(fabsf(v) < 1.0e3f)) bad++;   // NaN also counts
  }
  __shared__ int s;
  if (tid == 0) s = 0;
  __syncthreads();
  atomicAdd(&s, bad);
  __syncthreads();
  if (tid == 0) dflag[0] = (s > 32) ? 1 : 0;   // 1 = fp32 buffers, 0 = bf16 buffers
}

// ---------------- K0b: canonicalize all inputs to fp32 ----------------
struct CvtArgs { const void* src[11]; float* dst[11]; int n[11]; };
__global__ __launch_bounds__(256) void k_cvt(CvtArgs a, const int* __restrict__ dflag) {
  const int ai = blockIdx.y;
  const int n = a.n[ai];
  const int stride = gridDim.x * blockDim.x;
  const int f32 = dflag[0];
  float* dst = a.dst[ai];
  if (f32) {
    const float* src = (const float*)a.src[ai];
    for (int i = blockIdx.x * blockDim.x + threadIdx.x; i < n; i += stride) dst[i] = src[i];
  } else {
    const unsigned short* src = (const unsigned short*)a.src[ai];
    for (int i = blockIdx.x * blockDim.x + threadIdx.x; i < n; i += stride) dst[i] = bf1(src[i]);
  }
}

// ---------------- K1: transpose W_hh (512x1536 f32) -> WT (1536x512) bf16 ----------------
__global__ __launch_bounds__(1024) void k_transpose(const float* __restrict__ W,
                                                    __hip_bfloat16* __restrict__ WT) {
  __shared__ float tile[32][33];
  const int c0 = blockIdx.x * 32;   // col in [0,1536)
  const int k0 = blockIdx.y * 32;   // row in [0,512)
  tile[threadIdx.y][threadIdx.x] = W[(k0 + threadIdx.y) * G3 + c0 + threadIdx.x];
  __syncthreads();
  WT[(c0 + threadIdx.y) * DD + k0 + threadIdx.x] = __float2bfloat16(tile[threadIdx.x][threadIdx.y]);
}

// ---------------- K2: per-row fused encoder: m=relu(x@W0+b0); e=exp(tanh(m@W1+b1)@W2+b2) ----
__global__ __launch_bounds__(256) void k_encoder(const float* __restrict__ x,
    const float* __restrict__ W0, const float* __restrict__ b0,
    const float* __restrict__ W1, const float* __restrict__ b1,
    const float* __restrict__ W2, const float* __restrict__ b2,
    __hip_bfloat16* __restrict__ mo, float* __restrict__ e) {
  const int row = blockIdx.x;        // b*512+s
  const int tid = threadIdx.x;       // 256
  __shared__ float xs[IN_];
  __shared__ float ms[DD];
  __shared__ float as[DA];
  if (tid < IN_) xs[tid] = x[row * IN_ + tid];
  __syncthreads();
  const int d0 = tid * 2;
  float acc0 = 0.f, acc1 = 0.f;
  #pragma unroll 8
  for (int k = 0; k < IN_; k++) {
    const float xv = xs[k];
    const float2 w = *(const float2*)(W0 + k * DD + d0);
    acc0 = fmaf(xv, w.x, acc0);
    acc1 = fmaf(xv, w.y, acc1);
  }
  const float m0 = fmaxf(acc0 + b0[d0], 0.f);
  const float m1 = fmaxf(acc1 + b0[d0 + 1], 0.f);
  ms[d0] = m0; ms[d0 + 1] = m1;
  mo[row * DD + d0] = __float2bfloat16(m0);
  mo[row * DD + d0 + 1] = __float2bfloat16(m1);
  __syncthreads();
  if (tid < DA) {
    float a = b1[tid];
    #pragma unroll 4
    for (int k = 0; k < DD; k++) a = fmaf(ms[k], W1[k * DA + tid], a);
    as[tid] = tanhf(a);
  }
  __syncthreads();
  if (tid < RR) {
    float s = b2[tid];
    #pragma unroll
    for (int j = 0; j < DA; j++) s = fmaf(as[j], W2[j * RR + tid], s);
    e[row * RR + tid] = __expf(s);
  }
}

// ---------------- K3: per-(b,r) prefix scan -> inv[b,k,r] = 1/cumsum_k e ----------------
__global__ __launch_bounds__(64) void k_scan(const float* __restrict__ e, float* __restrict__ inv) {
  const int b = blockIdx.x / RR, r = blockIdx.x % RR;
  const int lane = threadIdx.x;  // 64
  float v[8];
  float sum = 0.f;
  #pragma unroll
  for (int i = 0; i < 8; i++) { v[i] = e[(b * SS + lane * 8 + i) * RR + r]; sum += v[i]; }
  float inc = sum;
  #pragma unroll
  for (int off = 1; off < 64; off <<= 1) {
    float n = __shfl_up(inc, off);
    if (lane >= off) inc += n;
  }
  float c = inc - sum;  // exclusive prefix
  #pragma unroll
  for (int i = 0; i < 8; i++) { c += v[i]; inv[(b * SS + lane * 8 + i) * RR + r] = 1.0f / c; }
}

// ---------------- K4: attention as streaming scan: M[t,d] = (1/R) sum_r cums(e*m)*inv ----
__global__ __launch_bounds__(128) void k_attn(const __hip_bfloat16* __restrict__ m,
    const float* __restrict__ e, const float* __restrict__ inv, __hip_bfloat16* __restrict__ M) {
  const int b = blockIdx.y;
  const int d = blockIdx.x * 128 + threadIdx.x;
  __shared__ float es[SS * RR];
  __shared__ float is[SS * RR];
  for (int i = threadIdx.x; i < SS * RR; i += 128) {
    es[i] = e[b * SS * RR + i];
    is[i] = inv[b * SS * RR + i];
  }
  __syncthreads();
  float num[RR];
  #pragma unroll
  for (int r = 0; r < RR; r++) num[r] = 0.f;
  const __hip_bfloat16* mb = m + (size_t)b * SS * DD + d;
  __hip_bfloat16* Mb = M + (size_t)b * SS * DD + d;
  for (int k = 0; k < SS; k++) {
    const float mv = __bfloat162float(mb[(size_t)k * DD]);
    float acc = 0.f;
    #pragma unroll
    for (int r = 0; r < RR; r++) {
      num[r] = fmaf(es[k * RR + r], mv, num[r]);
      acc = fmaf(num[r], is[k * RR + r], acc);
    }
    Mb[(size_t)k * DD] = __float2bfloat16(acc * (1.0f / RR));
  }
}

// ---------------- K5: gi = M @ W_ih + b_i  (8192x512 bf16 @ 512x1536 f32 -> GT) -------
template<typename GT>
__global__ __launch_bounds__(256) void k_gemm_gi(const __hip_bfloat16* __restrict__ A,
    const float* __restrict__ B, const float* __restrict__ bias,
    GT* __restrict__ C) {
  __shared__ __align__(16) float As[16][128];
  __shared__ __align__(16) float Bs[16][64];
  const int tid = threadIdx.x;
  const int bm = blockIdx.y * 128, bn = blockIdx.x * 64;
  const int tx = tid & 15, ty = tid >> 4;        // compute mapping: 8 rows x 4 cols
  const int ar = tid >> 1, ak = (tid & 1) * 8;   // A load mapping
  const int bk = tid >> 4, bn4 = (tid & 15) * 4; // B load mapping
  float acc[8][4];
  #pragma unroll
  for (int i = 0; i < 8; i++)
    #pragma unroll
    for (int j = 0; j < 4; j++) acc[i][j] = 0.f;
  const __hip_bfloat16* Arow = A + (size_t)(bm + ar) * DD + ak;
  const float* Bp = B + (size_t)bk * G3 + bn + bn4;
  for (int k0 = 0; k0 < DD; k0 += 16) {
    const uint4 a = *(const uint4*)(Arow + k0);          // 8 bf16
    const float4 bv = *(const float4*)(Bp + (size_t)k0 * G3);
    As[ak + 0][ar] = bflo(a.x); As[ak + 1][ar] = bfhi(a.x);
    As[ak + 2][ar] = bflo(a.y); As[ak + 3][ar] = bfhi(a.y);
    As[ak + 4][ar] = bflo(a.z); As[ak + 5][ar] = bfhi(a.z);
    As[ak + 6][ar] = bflo(a.w); As[ak + 7][ar] = bfhi(a.w);
    Bs[bk][bn4 + 0] = bv.x; Bs[bk][bn4 + 1] = bv.y;
    Bs[bk][bn4 + 2] = bv.z; Bs[bk][bn4 + 3] = bv.w;
    __syncthreads();
    #pragma unroll
    for (int kk = 0; kk < 16; kk++) {
      const float4 bv0 = *(const float4*)&Bs[kk][tx * 4];
      const float4 av0 = *(const float4*)&As[kk][ty * 8];
      const float4 av1 = *(const float4*)&As[kk][ty * 8 + 4];
      const float av[8] = {av0.x, av0.y, av0.z, av0.w, av1.x, av1.y, av1.z, av1.w};
      const float bw[4] = {bv0.x, bv0.y, bv0.z, bv0.w};
      #pragma unroll
      for (int i = 0; i < 8; i++)
        #pragma unroll
        for (int j = 0; j < 4; j++) acc[i][j] = fmaf(av[i], bw[j], acc[i][j]);
    }
    __syncthreads();
  }
  float b4[4];
  #pragma unroll
  for (int j = 0; j < 4; j++) b4[j] = bias[bn + tx * 4 + j];
  #pragma unroll
  for (int i = 0; i < 8; i++) {
    GT* cp = C + (size_t)(bm + ty * 8 + i) * G3 + bn + tx * 4;
    #pragma unroll
    for (int j = 0; j < 4; j++) stgi(cp + j, acc[i][j] + b4[j]);
  }
}

// ---------------- K6: persistent GRU, W_hh^T slice resident in LDS ----------------
// 32 j-slices x 16 batches = 512 blocks (2/CU). h double-buffered by step parity.
// Per-batch 32-block flag barrier per step; h exchange via agent-scope atomics (LLC).
template<typename GT>
__global__ __launch_bounds__(192) void k_gru(const __hip_bfloat16* __restrict__ WT,
    const GT* __restrict__ gi, const float* __restrict__ bh,
    float* __restrict__ hbuf, int* __restrict__ flags, void* __restrict__ outv,
    const int* __restrict__ dflag) {
  const int b = blockIdx.y, g = blockIdx.x, tid = threadIdx.x; // g<32
  const int f32o = dflag[0];
  __shared__ unsigned short Wl[48 * 516];   // 48 rows, stride 516 (pad: bank de-phase)
  __shared__ __align__(16) float hs[HH];
  __shared__ float ghs[48];
  __shared__ float gis[48];
  // preload W slice into LDS (once)
  for (int idx = tid; idx < 48 * 128; idx += 192) {
    const int c = idx >> 7, u = idx & 127;       // u: uint2 (4 bf16) index within row
    const int col = ((c >> 4) << 9) + (g << 4) + (c & 15);
    const uint2 w = *(const uint2*)(WT + (size_t)col * HH + u * 4);
    *(uint2*)&Wl[c * 516 + u * 4] = w;
  }
  const int c = tid >> 2, q = tid & 3;           // c<48, q<4 (k-quarter)
  float bhr = 0.f, bhz = 0.f, bhn = 0.f;
  if (tid < 16) {
    bhr = bh[(g << 4) + tid];
    bhz = bh[512 + (g << 4) + tid];
    bhn = bh[1024 + (g << 4) + tid];
  }
  float* h0 = hbuf + b * HH;
  float* h1 = hbuf + BB * HH + b * HH;
  int* cnt = flags + b * 64;                     // 256B-spaced per-batch counters
  const GT* gib = gi + (size_t)b * SS * G3;

  for (int t = 0; t < SS; t++) {
    float* hcur = (t & 1) ? h1 : h0;
    float* hnxt = (t & 1) ? h0 : h1;
    for (int i = tid; i < HH; i += 192)
      hs[i] = __hip_atomic_load(hcur + i, __ATOMIC_RELAXED, __HIP_MEMORY_SCOPE_AGENT);
    if (tid < 48) {
      const int col = ((tid >> 4) << 9) + (g << 4) + (tid & 15);
      gis[tid] = ldgi(gib + (size_t)t * G3 + col);
    }
    __syncthreads();
    // dot: row c of W slice, k in [q*128, q*128+128)
    float a0 = 0.f, a1 = 0.f, a2 = 0.f, a3 = 0.f;
    const uint2* wl = (const uint2*)&Wl[c * 516 + q * 128];
    const float4* h4 = (const float4*)&hs[q * 128];
    #pragma unroll
    for (int i = 0; i < 32; i++) {
      const uint2 w = wl[i];
      const float4 hv = h4[i];
      a0 = fmaf(hv.x, bflo(w.x), a0);
      a1 = fmaf(hv.y, bfhi(w.x), a1);
      a2 = fmaf(hv.z, bflo(w.y), a2);
      a3 = fmaf(hv.w, bfhi(w.y), a3);
    }
    float acc = (a0 + a1) + (a2 + a3);
    acc += __shfl_xor(acc, 1);
    acc += __shfl_xor(acc, 2);
    if (q == 0) ghs[c] = acc;
    __syncthreads();
    if (tid < 16) {
      const float ghr = ghs[tid] + bhr, ghz = ghs[16 + tid] + bhz, ghn = ghs[32 + tid] + bhn;
      const float gir = gis[tid], giz = gis[16 + tid], gin = gis[32 + tid];
      const float r = 1.f / (1.f + __expf(-(gir + ghr)));
      const float z = 1.f / (1.f + __expf(-(giz + ghz)));
      const float nx = gin + r * ghn;
      const float n = 1.f - 2.f / (__expf(2.f * nx) + 1.f);   // tanh
      const float hprev = hs[(g << 4) + tid];
      const float hnew = n + z * (hprev - n);
      __hip_atomic_store(hnxt + (g << 4) + tid, hnew, __ATOMIC_RELAXED, __HIP_MEMORY_SCOPE_AGENT);
      const size_t oi = ((size_t)b * SS + t) * HH + (g << 4) + tid;
      if (f32o) ((float*)outv)[oi] = hnew;
      else ((__hip_bfloat16*)outv)[oi] = __float2bfloat16(hnew);
    }
    __syncthreads();  // drains each thread's stores before arrival
    if (tid == 0) {
      __hip_atomic_fetch_add(cnt, 1, __ATOMIC_RELEASE, __HIP_MEMORY_SCOPE_AGENT);
      const int target = 32 * (t + 1);
      while (__hip_atomic_load(cnt, __ATOMIC_RELAXED, __HIP_MEMORY_SCOPE_AGENT) < target) {}
    }
    __syncthreads();
  }
}

extern "C" void kernel_launch(void* const* d_in, const int* in_sizes, int n_in,
                              void* d_out, int out_size, void* d_ws, size_t ws_size,
                              hipStream_t stream) {
  char* wsb = (char*)d_ws;
  float* hbuf = (float*)(wsb + OFF_H);
  int* flags  = (int*)(wsb + OFF_FL);
  int* dflag  = (int*)(wsb + OFF_DF);
  float* cx   = (float*)(wsb + OFF_CX);
  float* cW0  = (float*)(wsb + OFF_CW0);
  float* cb0  = (float*)(wsb + OFF_CB0);
  float* cW1  = (float*)(wsb + OFF_CW1);
  float* cb1  = (float*)(wsb + OFF_CB1);
  float* cW2  = (float*)(wsb + OFF_CW2);
  float* cb2  = (float*)(wsb + OFF_CB2);
  float* cWih = (float*)(wsb + OFF_CWIH);
  float* cWhh = (float*)(wsb + OFF_CWHH);
  float* cbi  = (float*)(wsb + OFF_CBI);
  float* cbh  = (float*)(wsb + OFF_CBH);
  __hip_bfloat16* WT = (__hip_bfloat16*)(wsb + OFF_WT);
  __hip_bfloat16* Mm = (__hip_bfloat16*)(wsb + OFF_MM);
  __hip_bfloat16* m  = (__hip_bfloat16*)(wsb + OFF_M);
  float* e   = (float*)(wsb + OFF_E);
  float* inv = (float*)(wsb + OFF_INV);
  void* gip  = (void*)(wsb + OFF_GI);
  const bool gi32 = (ws_size >= NEED_GI32);   // constant across calls -> same work every call

  // zero h double-buffer + sync counters (ws is poisoned 0xAA before every call)
  hipMemsetAsync(wsb, 0, 65536 + 4096, stream);

  k_detect<<<1, 1024, 0, stream>>>((const unsigned short*)d_in[0], dflag);

  CvtArgs ca;
  float* dsts[11] = {cx, cW0, cb0, cW1, cb1, cW2, cb2, cWih, cWhh, cbi, cbh};
  const int ns[11] = {BB * SS * IN_, IN_ * DD, DD, DD * DA, DA, DA * RR, RR,
                      DD * G3, HH * G3, G3, G3};
  for (int i = 0; i < 11; i++) { ca.src[i] = d_in[i]; ca.dst[i] = dsts[i]; ca.n[i] = ns[i]; }
  k_cvt<<<dim3(128, 11), 256, 0, stream>>>(ca, dflag);

  k_transpose<<<dim3(G3 / 32, DD / 32), dim3(32, 32), 0, stream>>>(cWhh, WT);
  k_encoder<<<BB * SS, 256, 0, stream>>>(cx, cW0, cb0, cW1, cb1, cW2, cb2, m, e);
  k_scan<<<BB * RR, 64, 0, stream>>>(e, inv);
  k_attn<<<dim3(4, BB), 128, 0, stream>>>(m, e, inv, Mm);
  if (gi32) {
    k_gemm_gi<float><<<dim3(G3 / 64, (BB * SS) / 128), 256, 0, stream>>>(Mm, cWih, cbi, (float*)gip);
    k_gru<float><<<dim3(32, BB), 192, 0, stream>>>(WT, (const float*)gip, cbh, hbuf, flags, d_out, dflag);
  } else {
    k_gemm_gi<__hip_bfloat16><<<dim3(G3 / 64, (BB * SS) / 128), 256, 0, stream>>>(Mm, cWih, cbi, (__hip_bfloat16*)gip);
    k_gru<__hip_bfloat16><<<dim3(32, BB), 192, 0, stream>>>(WT, (const __hip_bfloat16*)gip, cbh, hbuf, flags, d_out, dflag);
  }
}

// Round 4
// 2482.549 us; speedup vs baseline: 1.9711x; 1.9711x over previous
//
#include <hip/hip_runtime.h>
#include <hip/hip_bf16.h>

// Problem dims
#define BB 16
#define SS 512
#define IN_ 128
#define DD 512
#define HH 512
#define DA 30
#define RR 10
#define G3 1536   // 3*H

// ---- ws layout (bytes) ----
constexpr size_t OFF_H    = 0;              // h double-buffer [2][16][512] f32 : 65,536
constexpr size_t OFF_FL   = 65536;          // sync counters: 4,096
constexpr size_t OFF_DF   = 69632;          // dtype flag: 256
constexpr size_t OFF_CX   = 69888;          // canonical fp32 inputs:
constexpr size_t OFF_CW0  = OFF_CX   + 4194304;
constexpr size_t OFF_CB0  = OFF_CW0  + 262144;
constexpr size_t OFF_CW1  = OFF_CB0  + 2048;
constexpr size_t OFF_CB1  = OFF_CW1  + 61440;
constexpr size_t OFF_CW2  = OFF_CB1  + 256;
constexpr size_t OFF_CB2  = OFF_CW2  + 2048;
constexpr size_t OFF_CWIH = OFF_CB2  + 256;
constexpr size_t OFF_CWHH = OFF_CWIH + 3145728;
constexpr size_t OFF_CBI  = OFF_CWHH + 3145728;
constexpr size_t OFF_CBH  = OFF_CBI  + 6144;
constexpr size_t OFF_WT   = OFF_CBH  + 6144;          // W_hh^T bf16 [1536][512]
constexpr size_t OFF_MM   = OFF_WT   + 1572864;       // M bf16 [8192][512]
constexpr size_t OFF_BIG  = OFF_MM   + 8388608;
constexpr size_t OFF_M    = OFF_BIG;                  // m bf16 [8192][512]
constexpr size_t OFF_E    = OFF_BIG  + 8388608;       // e f32 [8192][10]
constexpr size_t OFF_INV  = OFF_E    + 327680;        // inv f32
constexpr size_t OFF_GI   = OFF_BIG;                  // gi aliases m/e/inv (dead after k_attn)
constexpr size_t NEED_GI32 = OFF_BIG + 50331648;      // gi fp32 total ~71.2 MB

__device__ __forceinline__ float bflo(unsigned int u) { return __uint_as_float(u << 16); }
__device__ __forceinline__ float bfhi(unsigned int u) { return __uint_as_float(u & 0xffff0000u); }
__device__ __forceinline__ float bf1(unsigned short u) { return __uint_as_float(((unsigned int)u) << 16); }

__device__ __forceinline__ float ldgi(const float* p) { return *p; }
__device__ __forceinline__ float ldgi(const __hip_bfloat16* p) { return __bfloat162float(*p); }
__device__ __forceinline__ void stgi(float* p, float v) { *p = v; }
__device__ __forceinline__ void stgi(__hip_bfloat16* p, float v) { *p = __float2bfloat16(v); }

// ---------------- K0a: detect input dtype. fp32 reinterpreted as bf16 -> ~45% huge/NaN. ----
__global__ __launch_bounds__(1024) void k_detect(const unsigned short* __restrict__ xs,
                                                 int* __restrict__ dflag) {
  const int tid = threadIdx.x;
  int bad = 0;
  for (int i = tid; i < 65536; i += 1024) {
    const float v = bf1(xs[i]);
    if (!(fabsf(v) < 1.0e3f)) bad++;   // NaN also counts
  }
  __shared__ int s;
  if (tid == 0) s = 0;
  __syncthreads();
  atomicAdd(&s, bad);
  __syncthreads();
  if (tid == 0) dflag[0] = (s > 32) ? 1 : 0;   // 1 = fp32 buffers, 0 = bf16 buffers
}

// ---------------- K0b: canonicalize all inputs to fp32 ----------------
struct CvtArgs { const void* src[11]; float* dst[11]; int n[11]; };
__global__ __launch_bounds__(256) void k_cvt(CvtArgs a, const int* __restrict__ dflag) {
  const int ai = blockIdx.y;
  const int n = a.n[ai];
  const int stride = gridDim.x * blockDim.x;
  const int f32 = dflag[0];
  float* dst = a.dst[ai];
  if (f32) {
    const float* src = (const float*)a.src[ai];
    for (int i = blockIdx.x * blockDim.x + threadIdx.x; i < n; i += stride) dst[i] = src[i];
  } else {
    const unsigned short* src = (const unsigned short*)a.src[ai];
    for (int i = blockIdx.x * blockDim.x + threadIdx.x; i < n; i += stride) dst[i] = bf1(src[i]);
  }
}

// ---------------- K1: transpose W_hh (512x1536 f32) -> WT (1536x512) bf16 ----------------
__global__ __launch_bounds__(1024) void k_transpose(const float* __restrict__ W,
                                                    __hip_bfloat16* __restrict__ WT) {
  __shared__ float tile[32][33];
  const int c0 = blockIdx.x * 32;   // col in [0,1536)
  const int k0 = blockIdx.y * 32;   // row in [0,512)
  tile[threadIdx.y][threadIdx.x] = W[(k0 + threadIdx.y) * G3 + c0 + threadIdx.x];
  __syncthreads();
  WT[(c0 + threadIdx.y) * DD + k0 + threadIdx.x] = __float2bfloat16(tile[threadIdx.x][threadIdx.y]);
}

// ---------------- K2: per-row fused encoder: m=relu(x@W0+b0); e=exp(tanh(m@W1+b1)@W2+b2) ----
__global__ __launch_bounds__(256) void k_encoder(const float* __restrict__ x,
    const float* __restrict__ W0, const float* __restrict__ b0,
    const float* __restrict__ W1, const float* __restrict__ b1,
    const float* __restrict__ W2, const float* __restrict__ b2,
    __hip_bfloat16* __restrict__ mo, float* __restrict__ e) {
  const int row = blockIdx.x;        // b*512+s
  const int tid = threadIdx.x;       // 256
  __shared__ float xs[IN_];
  __shared__ float ms[DD];
  __shared__ float as[DA];
  if (tid < IN_) xs[tid] = x[row * IN_ + tid];
  __syncthreads();
  const int d0 = tid * 2;
  float acc0 = 0.f, acc1 = 0.f;
  #pragma unroll 8
  for (int k = 0; k < IN_; k++) {
    const float xv = xs[k];
    const float2 w = *(const float2*)(W0 + k * DD + d0);
    acc0 = fmaf(xv, w.x, acc0);
    acc1 = fmaf(xv, w.y, acc1);
  }
  const float m0 = fmaxf(acc0 + b0[d0], 0.f);
  const float m1 = fmaxf(acc1 + b0[d0 + 1], 0.f);
  ms[d0] = m0; ms[d0 + 1] = m1;
  mo[row * DD + d0] = __float2bfloat16(m0);
  mo[row * DD + d0 + 1] = __float2bfloat16(m1);
  __syncthreads();
  if (tid < DA) {
    float a = b1[tid];
    #pragma unroll 4
    for (int k = 0; k < DD; k++) a = fmaf(ms[k], W1[k * DA + tid], a);
    as[tid] = tanhf(a);
  }
  __syncthreads();
  if (tid < RR) {
    float s = b2[tid];
    #pragma unroll
    for (int j = 0; j < DA; j++) s = fmaf(as[j], W2[j * RR + tid], s);
    e[row * RR + tid] = __expf(s);
  }
}

// ---------------- K3: per-(b,r) prefix scan -> inv[b,k,r] = 1/cumsum_k e ----------------
__global__ __launch_bounds__(64) void k_scan(const float* __restrict__ e, float* __restrict__ inv) {
  const int b = blockIdx.x / RR, r = blockIdx.x % RR;
  const int lane = threadIdx.x;  // 64
  float v[8];
  float sum = 0.f;
  #pragma unroll
  for (int i = 0; i < 8; i++) { v[i] = e[(b * SS + lane * 8 + i) * RR + r]; sum += v[i]; }
  float inc = sum;
  #pragma unroll
  for (int off = 1; off < 64; off <<= 1) {
    float n = __shfl_up(inc, off);
    if (lane >= off) inc += n;
  }
  float c = inc - sum;  // exclusive prefix
  #pragma unroll
  for (int i = 0; i < 8; i++) { c += v[i]; inv[(b * SS + lane * 8 + i) * RR + r] = 1.0f / c; }
}

// ---------------- K4: attention as streaming scan: M[t,d] = (1/R) sum_r cums(e*m)*inv ----
__global__ __launch_bounds__(128) void k_attn(const __hip_bfloat16* __restrict__ m,
    const float* __restrict__ e, const float* __restrict__ inv, __hip_bfloat16* __restrict__ M) {
  const int b = blockIdx.y;
  const int d = blockIdx.x * 128 + threadIdx.x;
  __shared__ float es[SS * RR];
  __shared__ float is[SS * RR];
  for (int i = threadIdx.x; i < SS * RR; i += 128) {
    es[i] = e[b * SS * RR + i];
    is[i] = inv[b * SS * RR + i];
  }
  __syncthreads();
  float num[RR];
  #pragma unroll
  for (int r = 0; r < RR; r++) num[r] = 0.f;
  const __hip_bfloat16* mb = m + (size_t)b * SS * DD + d;
  __hip_bfloat16* Mb = M + (size_t)b * SS * DD + d;
  for (int k = 0; k < SS; k++) {
    const float mv = __bfloat162float(mb[(size_t)k * DD]);
    float acc = 0.f;
    #pragma unroll
    for (int r = 0; r < RR; r++) {
      num[r] = fmaf(es[k * RR + r], mv, num[r]);
      acc = fmaf(num[r], is[k * RR + r], acc);
    }
    Mb[(size_t)k * DD] = __float2bfloat16(acc * (1.0f / RR));
  }
}

// ---------------- K5: gi = M @ W_ih + b_i  (8192x512 bf16 @ 512x1536 f32 -> GT) -------
template<typename GT>
__global__ __launch_bounds__(256) void k_gemm_gi(const __hip_bfloat16* __restrict__ A,
    const float* __restrict__ B, const float* __restrict__ bias,
    GT* __restrict__ C) {
  __shared__ __align__(16) float As[16][128];
  __shared__ __align__(16) float Bs[16][64];
  const int tid = threadIdx.x;
  const int bm = blockIdx.y * 128, bn = blockIdx.x * 64;
  const int tx = tid & 15, ty = tid >> 4;        // compute mapping: 8 rows x 4 cols
  const int ar = tid >> 1, ak = (tid & 1) * 8;   // A load mapping
  const int bk = tid >> 4, bn4 = (tid & 15) * 4; // B load mapping
  float acc[8][4];
  #pragma unroll
  for (int i = 0; i < 8; i++)
    #pragma unroll
    for (int j = 0; j < 4; j++) acc[i][j] = 0.f;
  const __hip_bfloat16* Arow = A + (size_t)(bm + ar) * DD + ak;
  const float* Bp = B + (size_t)bk * G3 + bn + bn4;
  for (int k0 = 0; k0 < DD; k0 += 16) {
    const uint4 a = *(const uint4*)(Arow + k0);          // 8 bf16
    const float4 bv = *(const float4*)(Bp + (size_t)k0 * G3);
    As[ak + 0][ar] = bflo(a.x); As[ak + 1][ar] = bfhi(a.x);
    As[ak + 2][ar] = bflo(a.y); As[ak + 3][ar] = bfhi(a.y);
    As[ak + 4][ar] = bflo(a.z); As[ak + 5][ar] = bfhi(a.z);
    As[ak + 6][ar] = bflo(a.w); As[ak + 7][ar] = bfhi(a.w);
    Bs[bk][bn4 + 0] = bv.x; Bs[bk][bn4 + 1] = bv.y;
    Bs[bk][bn4 + 2] = bv.z; Bs[bk][bn4 + 3] = bv.w;
    __syncthreads();
    #pragma unroll
    for (int kk = 0; kk < 16; kk++) {
      const float4 bv0 = *(const float4*)&Bs[kk][tx * 4];
      const float4 av0 = *(const float4*)&As[kk][ty * 8];
      const float4 av1 = *(const float4*)&As[kk][ty * 8 + 4];
      const float av[8] = {av0.x, av0.y, av0.z, av0.w, av1.x, av1.y, av1.z, av1.w};
      const float bw[4] = {bv0.x, bv0.y, bv0.z, bv0.w};
      #pragma unroll
      for (int i = 0; i < 8; i++)
        #pragma unroll
        for (int j = 0; j < 4; j++) acc[i][j] = fmaf(av[i], bw[j], acc[i][j]);
    }
    __syncthreads();
  }
  float b4[4];
  #pragma unroll
  for (int j = 0; j < 4; j++) b4[j] = bias[bn + tx * 4 + j];
  #pragma unroll
  for (int i = 0; i < 8; i++) {
    GT* cp = C + (size_t)(bm + ty * 8 + i) * G3 + bn + tx * 4;
    #pragma unroll
    for (int j = 0; j < 4; j++) stgi(cp + j, acc[i][j] + b4[j]);
  }
}

// ---------------- K6: persistent GRU, W_hh^T slice resident in REGISTERS ----------------
// 32 j-slices x 16 batches = 512 blocks (2/CU), 192 thr. Thread (c,q): row col, k-quarter q,
// 128 bf16 of W in 16 uint4 VGPRs. h in padded LDS quarters [4][132] (broadcast, conflict-
// free). Barrier: sc1 stores + wave-level vmcnt drain + RELAXED LLC fetch_add (no wbl2!).
// gi prefetched one step ahead by wave 1.
template<typename GT>
__global__ __launch_bounds__(192) void k_gru(const __hip_bfloat16* __restrict__ WT,
    const GT* __restrict__ gi, const float* __restrict__ bh,
    float* __restrict__ hbuf, int* __restrict__ flags, void* __restrict__ outv,
    const int* __restrict__ dflag) {
  const int b = blockIdx.y, g = blockIdx.x, tid = threadIdx.x; // g<32
  const int f32o = dflag[0];
  const int c = tid >> 2, q = tid & 3;           // row c<48, k-quarter q<4
  const int col = ((c >> 4) << 9) + (g << 4) + (c & 15);
  __shared__ __align__(16) float hs4[4 * 132];   // h in 4 padded quarters
  __shared__ float ghs[48];
  __shared__ float gis[48];
  // W quarter-row resident in registers: 128 bf16 = 16 uint4 (64 VGPRs)
  uint4 wr[16];
  {
    const uint4* wp = (const uint4*)(WT + (size_t)col * HH + q * 128);
    #pragma unroll
    for (int i = 0; i < 16; i++) wr[i] = wp[i];
  }
  const float bias_c = bh[col];
  // wave-1 gi prefetch lane mapping (tid 64..111 <-> slot 0..47)
  const int pslot = tid - 64;
  const bool pf = (pslot >= 0 && pslot < 48);
  const int gcol = pf ? (((pslot >> 4) << 9) + (g << 4) + (pslot & 15)) : 0;
  float* h0 = hbuf + b * HH;
  float* h1 = hbuf + BB * HH + b * HH;
  int* cnt = flags + b * 64;                     // 256B-spaced per-batch counters
  const GT* gib = gi + (size_t)b * SS * G3;
  float gpre = pf ? ldgi(gib + gcol) : 0.f;

  for (int t = 0; t < SS; t++) {
    float* hcur = (t & 1) ? h1 : h0;
    float* hnxt = (t & 1) ? h0 : h1;
    // stage h_{t-1} into padded LDS (sc1 atomic loads -> LLC-fresh)
    #pragma unroll
    for (int u = 0; u < 3; u++) {
      const int i = tid + u * 192;
      if (i < HH) {
        const float v = __hip_atomic_load(hcur + i, __ATOMIC_RELAXED, __HIP_MEMORY_SCOPE_AGENT);
        hs4[(i >> 7) * 132 + (i & 127)] = v;
      }
    }
    if (pf) gis[pslot] = gpre;
    __syncthreads();                                    // #1
    if (pf && t + 1 < SS) gpre = ldgi(gib + (size_t)(t + 1) * G3 + gcol);  // overlap dot
    // dot: row col, k in [q*128, q*128+128)
    float a0 = 0.f, a1 = 0.f, a2 = 0.f, a3 = 0.f;
    const float4* hp = (const float4*)&hs4[q * 132];
    #pragma unroll
    for (int i = 0; i < 16; i++) {
      const uint4 w = wr[i];
      const float4 ha = hp[2 * i];
      const float4 hb = hp[2 * i + 1];
      a0 = fmaf(ha.x, bflo(w.x), a0); a1 = fmaf(ha.y, bfhi(w.x), a1);
      a2 = fmaf(ha.z, bflo(w.y), a2); a3 = fmaf(ha.w, bfhi(w.y), a3);
      a0 = fmaf(hb.x, bflo(w.z), a0); a1 = fmaf(hb.y, bfhi(w.z), a1);
      a2 = fmaf(hb.z, bflo(w.w), a2); a3 = fmaf(hb.w, bfhi(w.w), a3);
    }
    float acc = (a0 + a1) + (a2 + a3);
    acc += __shfl_xor(acc, 1);   // reduce across q (lane bits 0..1)
    acc += __shfl_xor(acc, 2);
    if (q == 0) ghs[c] = acc + bias_c;
    __syncthreads();                                    // #2
    if (tid < 16) {
      const float ghr = ghs[tid], ghz = ghs[16 + tid], ghn = ghs[32 + tid];
      const float gir = gis[tid], giz = gis[16 + tid], gin = gis[32 + tid];
      const float r = 1.f / (1.f + __expf(-(gir + ghr)));
      const float z = 1.f / (1.f + __expf(-(giz + ghz)));
      const float nx = gin + r * ghn;
      const float n = 1.f - 2.f / (__expf(2.f * nx) + 1.f);   // tanh
      const int j = (g << 4) + tid;
      const float hprev = hs4[(j >> 7) * 132 + (j & 127)];
      const float hnew = n + z * (hprev - n);
      __hip_atomic_store(hnxt + j, hnew, __ATOMIC_RELAXED, __HIP_MEMORY_SCOPE_AGENT);
      const size_t oi = ((size_t)b * SS + t) * HH + j;
      if (f32o) ((float*)outv)[oi] = hnew;
      else ((__hip_bfloat16*)outv)[oi] = __float2bfloat16(hnew);
    }
    // wave 0 drains its h-stores (sc1 -> at LLC once vmcnt==0), then tid0 arrives.
    if (tid < 64) {
      asm volatile("s_waitcnt vmcnt(0)" ::: "memory");
      if (tid == 0)
        __hip_atomic_fetch_add(cnt, 1, __ATOMIC_RELAXED, __HIP_MEMORY_SCOPE_AGENT);
    }
    if (tid == 0) {
      const int target = 32 * (t + 1);
      while (__hip_atomic_load(cnt, __ATOMIC_RELAXED, __HIP_MEMORY_SCOPE_AGENT) < target) {}
    }
    __syncthreads();                                    // #3 release whole block
  }
}

extern "C" void kernel_launch(void* const* d_in, const int* in_sizes, int n_in,
                              void* d_out, int out_size, void* d_ws, size_t ws_size,
                              hipStream_t stream) {
  char* wsb = (char*)d_ws;
  float* hbuf = (float*)(wsb + OFF_H);
  int* flags  = (int*)(wsb + OFF_FL);
  int* dflag  = (int*)(wsb + OFF_DF);
  float* cx   = (float*)(wsb + OFF_CX);
  float* cW0  = (float*)(wsb + OFF_CW0);
  float* cb0  = (float*)(wsb + OFF_CB0);
  float* cW1  = (float*)(wsb + OFF_CW1);
  float* cb1  = (float*)(wsb + OFF_CB1);
  float* cW2  = (float*)(wsb + OFF_CW2);
  float* cb2  = (float*)(wsb + OFF_CB2);
  float* cWih = (float*)(wsb + OFF_CWIH);
  float* cWhh = (float*)(wsb + OFF_CWHH);
  float* cbi  = (float*)(wsb + OFF_CBI);
  float* cbh  = (float*)(wsb + OFF_CBH);
  __hip_bfloat16* WT = (__hip_bfloat16*)(wsb + OFF_WT);
  __hip_bfloat16* Mm = (__hip_bfloat16*)(wsb + OFF_MM);
  __hip_bfloat16* m  = (__hip_bfloat16*)(wsb + OFF_M);
  float* e   = (float*)(wsb + OFF_E);
  float* inv = (float*)(wsb + OFF_INV);
  void* gip  = (void*)(wsb + OFF_GI);
  const bool gi32 = (ws_size >= NEED_GI32);   // constant across calls -> same work every call

  // zero h double-buffer + sync counters (ws is poisoned 0xAA before every call)
  hipMemsetAsync(wsb, 0, 65536 + 4096, stream);

  k_detect<<<1, 1024, 0, stream>>>((const unsigned short*)d_in[0], dflag);

  CvtArgs ca;
  float* dsts[11] = {cx, cW0, cb0, cW1, cb1, cW2, cb2, cWih, cWhh, cbi, cbh};
  const int ns[11] = {BB * SS * IN_, IN_ * DD, DD, DD * DA, DA, DA * RR, RR,
                      DD * G3, HH * G3, G3, G3};
  for (int i = 0; i < 11; i++) { ca.src[i] = d_in[i]; ca.dst[i] = dsts[i]; ca.n[i] = ns[i]; }
  k_cvt<<<dim3(128, 11), 256, 0, stream>>>(ca, dflag);

  k_transpose<<<dim3(G3 / 32, DD / 32), dim3(32, 32), 0, stream>>>(cWhh, WT);
  k_encoder<<<BB * SS, 256, 0, stream>>>(cx, cW0, cb0, cW1, cb1, cW2, cb2, m, e);
  k_scan<<<BB * RR, 64, 0, stream>>>(e, inv);
  k_attn<<<dim3(4, BB), 128, 0, stream>>>(m, e, inv, Mm);
  if (gi32) {
    k_gemm_gi<float><<<dim3(G3 / 64, (BB * SS) / 128), 256, 0, stream>>>(Mm, cWih, cbi, (float*)gip);
    k_gru<float><<<dim3(32, BB), 192, 0, stream>>>(WT, (const float*)gip, cbh, hbuf, flags, d_out, dflag);
  } else {
    k_gemm_gi<__hip_bfloat16><<<dim3(G3 / 64, (BB * SS) / 128), 256, 0, stream>>>(Mm, cWih, cbi, (__hip_bfloat16*)gip);
    k_gru<__hip_bfloat16><<<dim3(32, BB), 192, 0, stream>>>(WT, (const __hip_bfloat16*)gip, cbh, hbuf, flags, d_out, dflag);
  }
}

// Round 5
// 1936.834 us; speedup vs baseline: 2.5265x; 1.2818x over previous
//
#include <hip/hip_runtime.h>
#include <hip/hip_bf16.h>

// Problem dims
#define BB 16
#define SS 512
#define IN_ 128
#define DD 512
#define HH 512
#define DA 30
#define RR 10
#define G3 1536   // 3*H

// ---- ws layout (bytes) ----
constexpr size_t OFF_H    = 0;                        // tagged h ring u64[2][16][512]: 131,072
constexpr size_t OFF_DF   = 131072;                   // dtype flag: 256
constexpr size_t OFF_CX   = OFF_DF   + 256;           // canonical fp32 inputs
constexpr size_t OFF_CW0  = OFF_CX   + 4194304;
constexpr size_t OFF_CB0  = OFF_CW0  + 262144;
constexpr size_t OFF_CW1  = OFF_CB0  + 2048;
constexpr size_t OFF_CB1  = OFF_CW1  + 61440;
constexpr size_t OFF_CW2  = OFF_CB1  + 256;
constexpr size_t OFF_CB2  = OFF_CW2  + 2048;
constexpr size_t OFF_CWIH = OFF_CB2  + 256;
constexpr size_t OFF_CWHH = OFF_CWIH + 3145728;
constexpr size_t OFF_CBI  = OFF_CWHH + 3145728;
constexpr size_t OFF_CBH  = OFF_CBI  + 6144;
constexpr size_t OFF_WT   = OFF_CBH  + 6144;          // W_hh^T bf16 [1536][512]
constexpr size_t OFF_MM   = OFF_WT   + 1572864;       // M bf16 [8192][512]
constexpr size_t OFF_BIG  = OFF_MM   + 8388608;
constexpr size_t OFF_M    = OFF_BIG;                  // m bf16 [8192][512]
constexpr size_t OFF_E    = OFF_BIG  + 8388608;       // e f32 [8192][10]
constexpr size_t OFF_INV  = OFF_E    + 327680;        // inv f32
constexpr size_t OFF_GI   = OFF_BIG;                  // gi aliases m/e/inv (dead after k_attn)
constexpr size_t NEED_GI32 = OFF_BIG + 50331648;      // gi fp32 path total

__device__ __forceinline__ float bflo(unsigned int u) { return __uint_as_float(u << 16); }
__device__ __forceinline__ float bfhi(unsigned int u) { return __uint_as_float(u & 0xffff0000u); }
__device__ __forceinline__ float bf1(unsigned short u) { return __uint_as_float(((unsigned int)u) << 16); }

__device__ __forceinline__ float ldgi(const float* p) { return *p; }
__device__ __forceinline__ float ldgi(const __hip_bfloat16* p) { return __bfloat162float(*p); }
__device__ __forceinline__ void stgi(float* p, float v) { *p = v; }
__device__ __forceinline__ void stgi(__hip_bfloat16* p, float v) { *p = __float2bfloat16(v); }

// ---------------- K0a: detect input dtype. fp32 reinterpreted as bf16 -> ~45% huge/NaN. ----
__global__ __launch_bounds__(256) void k_detect(const unsigned short* __restrict__ xs,
                                                int* __restrict__ dflag) {
  const int tid = threadIdx.x;
  int bad = 0;
  for (int i = tid; i < 8192; i += 256) {
    const float v = bf1(xs[i]);
    if (!(fabsf(v) < 1.0e3f)) bad++;   // NaN also counts
  }
  __shared__ int s;
  if (tid == 0) s = 0;
  __syncthreads();
  atomicAdd(&s, bad);
  __syncthreads();
  if (tid == 0) dflag[0] = (s > 16) ? 1 : 0;   // 1 = fp32 buffers, 0 = bf16 buffers
}

// ---------------- K0b: canonicalize all inputs to fp32 ----------------
struct CvtArgs { const void* src[11]; float* dst[11]; int n[11]; };
__global__ __launch_bounds__(256) void k_cvt(CvtArgs a, const int* __restrict__ dflag) {
  const int ai = blockIdx.y;
  const int n = a.n[ai];
  const int stride = gridDim.x * blockDim.x;
  const int f32 = dflag[0];
  float* dst = a.dst[ai];
  if (f32) {
    const float* src = (const float*)a.src[ai];
    for (int i = blockIdx.x * blockDim.x + threadIdx.x; i < n; i += stride) dst[i] = src[i];
  } else {
    const unsigned short* src = (const unsigned short*)a.src[ai];
    for (int i = blockIdx.x * blockDim.x + threadIdx.x; i < n; i += stride) dst[i] = bf1(src[i]);
  }
}

// ---------------- K1: transpose W_hh (512x1536 f32) -> WT (1536x512) bf16 ----------------
__global__ __launch_bounds__(1024) void k_transpose(const float* __restrict__ W,
                                                    __hip_bfloat16* __restrict__ WT) {
  __shared__ float tile[32][33];
  const int c0 = blockIdx.x * 32;   // col in [0,1536)
  const int k0 = blockIdx.y * 32;   // row in [0,512)
  tile[threadIdx.y][threadIdx.x] = W[(k0 + threadIdx.y) * G3 + c0 + threadIdx.x];
  __syncthreads();
  WT[(c0 + threadIdx.y) * DD + k0 + threadIdx.x] = __float2bfloat16(tile[threadIdx.x][threadIdx.y]);
}

// ---------------- K2: per-row fused encoder: m=relu(x@W0+b0); e=exp(tanh(m@W1+b1)@W2+b2) ----
__global__ __launch_bounds__(256) void k_encoder(const float* __restrict__ x,
    const float* __restrict__ W0, const float* __restrict__ b0,
    const float* __restrict__ W1, const float* __restrict__ b1,
    const float* __restrict__ W2, const float* __restrict__ b2,
    __hip_bfloat16* __restrict__ mo, float* __restrict__ e) {
  const int row = blockIdx.x;        // b*512+s
  const int tid = threadIdx.x;       // 256
  __shared__ float xs[IN_];
  __shared__ float ms[DD];
  __shared__ float as[DA];
  if (tid < IN_) xs[tid] = x[row * IN_ + tid];
  __syncthreads();
  const int d0 = tid * 2;
  float acc0 = 0.f, acc1 = 0.f;
  #pragma unroll 8
  for (int k = 0; k < IN_; k++) {
    const float xv = xs[k];
    const float2 w = *(const float2*)(W0 + k * DD + d0);
    acc0 = fmaf(xv, w.x, acc0);
    acc1 = fmaf(xv, w.y, acc1);
  }
  const float m0 = fmaxf(acc0 + b0[d0], 0.f);
  const float m1 = fmaxf(acc1 + b0[d0 + 1], 0.f);
  ms[d0] = m0; ms[d0 + 1] = m1;
  mo[row * DD + d0] = __float2bfloat16(m0);
  mo[row * DD + d0 + 1] = __float2bfloat16(m1);
  __syncthreads();
  if (tid < DA) {
    float a = b1[tid];
    #pragma unroll 4
    for (int k = 0; k < DD; k++) a = fmaf(ms[k], W1[k * DA + tid], a);
    as[tid] = tanhf(a);
  }
  __syncthreads();
  if (tid < RR) {
    float s = b2[tid];
    #pragma unroll
    for (int j = 0; j < DA; j++) s = fmaf(as[j], W2[j * RR + tid], s);
    e[row * RR + tid] = __expf(s);
  }
}

// ---------------- K3: per-(b,r) prefix scan -> inv[b,k,r] = 1/cumsum_k e ----------------
__global__ __launch_bounds__(64) void k_scan(const float* __restrict__ e, float* __restrict__ inv) {
  const int b = blockIdx.x / RR, r = blockIdx.x % RR;
  const int lane = threadIdx.x;  // 64
  float v[8];
  float sum = 0.f;
  #pragma unroll
  for (int i = 0; i < 8; i++) { v[i] = e[(b * SS + lane * 8 + i) * RR + r]; sum += v[i]; }
  float inc = sum;
  #pragma unroll
  for (int off = 1; off < 64; off <<= 1) {
    float n = __shfl_up(inc, off);
    if (lane >= off) inc += n;
  }
  float c = inc - sum;  // exclusive prefix
  #pragma unroll
  for (int i = 0; i < 8; i++) { c += v[i]; inv[(b * SS + lane * 8 + i) * RR + r] = 1.0f / c; }
}

// ---------------- K4: attention as streaming scan: M[t,d] = (1/R) sum_r cums(e*m)*inv ----
__global__ __launch_bounds__(128) void k_attn(const __hip_bfloat16* __restrict__ m,
    const float* __restrict__ e, const float* __restrict__ inv, __hip_bfloat16* __restrict__ M) {
  const int b = blockIdx.y;
  const int d = blockIdx.x * 128 + threadIdx.x;
  __shared__ float es[SS * RR];
  __shared__ float is[SS * RR];
  for (int i = threadIdx.x; i < SS * RR; i += 128) {
    es[i] = e[b * SS * RR + i];
    is[i] = inv[b * SS * RR + i];
  }
  __syncthreads();
  float num[RR];
  #pragma unroll
  for (int r = 0; r < RR; r++) num[r] = 0.f;
  const __hip_bfloat16* mb = m + (size_t)b * SS * DD + d;
  __hip_bfloat16* Mb = M + (size_t)b * SS * DD + d;
  for (int k = 0; k < SS; k++) {
    const float mv = __bfloat162float(mb[(size_t)k * DD]);
    float acc = 0.f;
    #pragma unroll
    for (int r = 0; r < RR; r++) {
      num[r] = fmaf(es[k * RR + r], mv, num[r]);
      acc = fmaf(num[r], is[k * RR + r], acc);
    }
    Mb[(size_t)k * DD] = __float2bfloat16(acc * (1.0f / RR));
  }
}

// ---------------- K5: gi = M @ W_ih + b_i  (8192x512 bf16 @ 512x1536 f32 -> GT) -------
template<typename GT>
__global__ __launch_bounds__(256) void k_gemm_gi(const __hip_bfloat16* __restrict__ A,
    const float* __restrict__ B, const float* __restrict__ bias,
    GT* __restrict__ C) {
  __shared__ __align__(16) float As[16][128];
  __shared__ __align__(16) float Bs[16][64];
  const int tid = threadIdx.x;
  const int bm = blockIdx.y * 128, bn = blockIdx.x * 64;
  const int tx = tid & 15, ty = tid >> 4;        // compute mapping: 8 rows x 4 cols
  const int ar = tid >> 1, ak = (tid & 1) * 8;   // A load mapping
  const int bk = tid >> 4, bn4 = (tid & 15) * 4; // B load mapping
  float acc[8][4];
  #pragma unroll
  for (int i = 0; i < 8; i++)
    #pragma unroll
    for (int j = 0; j < 4; j++) acc[i][j] = 0.f;
  const __hip_bfloat16* Arow = A + (size_t)(bm + ar) * DD + ak;
  const float* Bp = B + (size_t)bk * G3 + bn + bn4;
  for (int k0 = 0; k0 < DD; k0 += 16) {
    const uint4 a = *(const uint4*)(Arow + k0);          // 8 bf16
    const float4 bv = *(const float4*)(Bp + (size_t)k0 * G3);
    As[ak + 0][ar] = bflo(a.x); As[ak + 1][ar] = bfhi(a.x);
    As[ak + 2][ar] = bflo(a.y); As[ak + 3][ar] = bfhi(a.y);
    As[ak + 4][ar] = bflo(a.z); As[ak + 5][ar] = bfhi(a.z);
    As[ak + 6][ar] = bflo(a.w); As[ak + 7][ar] = bfhi(a.w);
    Bs[bk][bn4 + 0] = bv.x; Bs[bk][bn4 + 1] = bv.y;
    Bs[bk][bn4 + 2] = bv.z; Bs[bk][bn4 + 3] = bv.w;
    __syncthreads();
    #pragma unroll
    for (int kk = 0; kk < 16; kk++) {
      const float4 bv0 = *(const float4*)&Bs[kk][tx * 4];
      const float4 av0 = *(const float4*)&As[kk][ty * 8];
      const float4 av1 = *(const float4*)&As[kk][ty * 8 + 4];
      const float av[8] = {av0.x, av0.y, av0.z, av0.w, av1.x, av1.y, av1.z, av1.w};
      const float bw[4] = {bv0.x, bv0.y, bv0.z, bv0.w};
      #pragma unroll
      for (int i = 0; i < 8; i++)
        #pragma unroll
        for (int j = 0; j < 4; j++) acc[i][j] = fmaf(av[i], bw[j], acc[i][j]);
    }
    __syncthreads();
  }
  float b4[4];
  #pragma unroll
  for (int j = 0; j < 4; j++) b4[j] = bias[bn + tx * 4 + j];
  #pragma unroll
  for (int i = 0; i < 8; i++) {
    GT* cp = C + (size_t)(bm + ty * 8 + i) * G3 + bn + tx * 4;
    #pragma unroll
    for (int j = 0; j < 4; j++) stgi(cp + j, acc[i][j] + b4[j]);
  }
}

// ---------------- K6: persistent GRU, tagged-value sync (single-RTT handshake) ----------
// 32 j-slices x 16 batches = 512 blocks, 192 thr. W quarter-rows in VGPRs (16 uint4/thr).
// h exchanged as u64 (tag<<32 | f32 bits) in a parity-2 ring: readers poll the data itself,
// so detection+value = ONE LLC round trip. No counter, no vmcnt drain, no fetch_add.
// Ring-2 safety: producer can write tag t+2 only after reading all tag t+1, which requires
// every block (all are producer+reader) to have consumed tag t.
template<typename GT>
__global__ __launch_bounds__(192) void k_gru(const __hip_bfloat16* __restrict__ WT,
    const GT* __restrict__ gi, const float* __restrict__ bh,
    unsigned long long* __restrict__ hslots, void* __restrict__ outv,
    const int* __restrict__ dflag) {
  const int b = blockIdx.y, g = blockIdx.x, tid = threadIdx.x; // g<32
  const int f32o = dflag[0];
  const int c = tid >> 2, q = tid & 3;           // row c<48, k-quarter q<4
  const int col = ((c >> 4) << 9) + (g << 4) + (c & 15);
  __shared__ __align__(16) float hs4[4 * 132];   // h in 4 padded quarters
  __shared__ float ghs[48];
  __shared__ float gis[48];
  // W quarter-row resident in registers: 128 bf16 = 16 uint4 (64 VGPRs)
  uint4 wr[16];
  {
    const uint4* wp = (const uint4*)(WT + (size_t)col * HH + q * 128);
    #pragma unroll
    for (int i = 0; i < 16; i++) wr[i] = wp[i];
  }
  const float bias_c = bh[col];
  // wave-2 gi prefetch lane mapping (tid 128..175 <-> slot 0..47); waves 0-1 poll h.
  const int pslot = tid - 128;
  const bool pf = (pslot >= 0 && pslot < 48);
  const int gcol = pf ? (((pslot >> 4) << 9) + (g << 4) + (pslot & 15)) : 0;
  unsigned long long* s0 = hslots + b * HH;
  unsigned long long* s1 = hslots + BB * HH + b * HH;
  const GT* gib = gi + (size_t)b * SS * G3;
  float gpre = pf ? ldgi(gib + gcol) : 0.f;

  for (int t = 0; t < SS; t++) {
    unsigned long long* cur = (t & 1) ? s1 : s0;
    unsigned long long* nxt = (t & 1) ? s0 : s1;
    // poll+stage h_t: 128 threads x 4 slots, tag==t means value valid
    if (tid < 128) {
      unsigned long long v[4];
      #pragma unroll
      for (int u = 0; u < 4; u++)
        v[u] = __hip_atomic_load(cur + tid + u * 128, __ATOMIC_RELAXED, __HIP_MEMORY_SCOPE_AGENT);
      #pragma unroll
      for (int u = 0; u < 4; u++) {
        while ((unsigned)(v[u] >> 32) != (unsigned)t)
          v[u] = __hip_atomic_load(cur + tid + u * 128, __ATOMIC_RELAXED, __HIP_MEMORY_SCOPE_AGENT);
        hs4[u * 132 + tid] = __uint_as_float((unsigned)v[u]);
      }
    }
    if (pf) gis[pslot] = gpre;
    __syncthreads();                                    // #1
    if (pf && t + 1 < SS) gpre = ldgi(gib + (size_t)(t + 1) * G3 + gcol);  // overlap dot
    // dot: row col, k in [q*128, q*128+128)
    float a0 = 0.f, a1 = 0.f, a2 = 0.f, a3 = 0.f;
    const float4* hp = (const float4*)&hs4[q * 132];
    #pragma unroll
    for (int i = 0; i < 16; i++) {
      const uint4 w = wr[i];
      const float4 ha = hp[2 * i];
      const float4 hb = hp[2 * i + 1];
      a0 = fmaf(ha.x, bflo(w.x), a0); a1 = fmaf(ha.y, bfhi(w.x), a1);
      a2 = fmaf(ha.z, bflo(w.y), a2); a3 = fmaf(ha.w, bfhi(w.y), a3);
      a0 = fmaf(hb.x, bflo(w.z), a0); a1 = fmaf(hb.y, bfhi(w.z), a1);
      a2 = fmaf(hb.z, bflo(w.w), a2); a3 = fmaf(hb.w, bfhi(w.w), a3);
    }
    float acc = (a0 + a1) + (a2 + a3);
    acc += __shfl_xor(acc, 1);   // reduce across q (lane bits 0..1)
    acc += __shfl_xor(acc, 2);
    if (q == 0) ghs[c] = acc + bias_c;
    __syncthreads();                                    // #2
    if (tid < 16) {
      const float ghr = ghs[tid], ghz = ghs[16 + tid], ghn = ghs[32 + tid];
      const float gir = gis[tid], giz = gis[16 + tid], gin = gis[32 + tid];
      const float r = 1.f / (1.f + __expf(-(gir + ghr)));
      const float z = 1.f / (1.f + __expf(-(giz + ghz)));
      const float nx = gin + r * ghn;
      const float n = 1.f - 2.f / (__expf(2.f * nx) + 1.f);   // tanh
      const int j = (g << 4) + tid;
      const float hprev = hs4[(j >> 7) * 132 + (j & 127)];
      const float hnew = n + z * (hprev - n);
      const unsigned long long pk =
          ((unsigned long long)(unsigned)(t + 1) << 32) | (unsigned long long)__float_as_uint(hnew);
      __hip_atomic_store(nxt + j, pk, __ATOMIC_RELAXED, __HIP_MEMORY_SCOPE_AGENT);
      const size_t oi = ((size_t)b * SS + t) * HH + j;
      if (f32o) ((float*)outv)[oi] = hnew;
      else ((__hip_bfloat16*)outv)[oi] = __float2bfloat16(hnew);
    }
    __syncthreads();                                    // #3 (hs4 WAR before next stage)
  }
}

extern "C" void kernel_launch(void* const* d_in, const int* in_sizes, int n_in,
                              void* d_out, int out_size, void* d_ws, size_t ws_size,
                              hipStream_t stream) {
  char* wsb = (char*)d_ws;
  unsigned long long* hslots = (unsigned long long*)(wsb + OFF_H);
  int* dflag  = (int*)(wsb + OFF_DF);
  float* cx   = (float*)(wsb + OFF_CX);
  float* cW0  = (float*)(wsb + OFF_CW0);
  float* cb0  = (float*)(wsb + OFF_CB0);
  float* cW1  = (float*)(wsb + OFF_CW1);
  float* cb1  = (float*)(wsb + OFF_CB1);
  float* cW2  = (float*)(wsb + OFF_CW2);
  float* cb2  = (float*)(wsb + OFF_CB2);
  float* cWih = (float*)(wsb + OFF_CWIH);
  float* cWhh = (float*)(wsb + OFF_CWHH);
  float* cbi  = (float*)(wsb + OFF_CBI);
  float* cbh  = (float*)(wsb + OFF_CBH);
  __hip_bfloat16* WT = (__hip_bfloat16*)(wsb + OFF_WT);
  __hip_bfloat16* Mm = (__hip_bfloat16*)(wsb + OFF_MM);
  __hip_bfloat16* m  = (__hip_bfloat16*)(wsb + OFF_M);
  float* e   = (float*)(wsb + OFF_E);
  float* inv = (float*)(wsb + OFF_INV);
  void* gip  = (void*)(wsb + OFF_GI);
  const bool gi32 = (ws_size >= NEED_GI32);   // constant across calls -> same work every call

  // zero tagged h ring (tag 0 == valid h_0 = 0). ws is poisoned 0xAA before every call.
  hipMemsetAsync(wsb, 0, 131072, stream);

  k_detect<<<1, 256, 0, stream>>>((const unsigned short*)d_in[0], dflag);

  CvtArgs ca;
  float* dsts[11] = {cx, cW0, cb0, cW1, cb1, cW2, cb2, cWih, cWhh, cbi, cbh};
  const int ns[11] = {BB * SS * IN_, IN_ * DD, DD, DD * DA, DA, DA * RR, RR,
                      DD * G3, HH * G3, G3, G3};
  for (int i = 0; i < 11; i++) { ca.src[i] = d_in[i]; ca.dst[i] = dsts[i]; ca.n[i] = ns[i]; }
  k_cvt<<<dim3(128, 11), 256, 0, stream>>>(ca, dflag);

  k_transpose<<<dim3(G3 / 32, DD / 32), dim3(32, 32), 0, stream>>>(cWhh, WT);
  k_encoder<<<BB * SS, 256, 0, stream>>>(cx, cW0, cb0, cW1, cb1, cW2, cb2, m, e);
  k_scan<<<BB * RR, 64, 0, stream>>>(e, inv);
  k_attn<<<dim3(4, BB), 128, 0, stream>>>(m, e, inv, Mm);
  if (gi32) {
    k_gemm_gi<float><<<dim3(G3 / 64, (BB * SS) / 128), 256, 0, stream>>>(Mm, cWih, cbi, (float*)gip);
    k_gru<float><<<dim3(32, BB), 192, 0, stream>>>(WT, (const float*)gip, cbh, hslots, d_out, dflag);
  } else {
    k_gemm_gi<__hip_bfloat16><<<dim3(G3 / 64, (BB * SS) / 128), 256, 0, stream>>>(Mm, cWih, cbi, (__hip_bfloat16*)gip);
    k_gru<__hip_bfloat16><<<dim3(32, BB), 192, 0, stream>>>(WT, (const __hip_bfloat16*)gip, cbh, hslots, d_out, dflag);
  }
}

// Round 7
// 1515.961 us; speedup vs baseline: 3.2279x; 1.2776x over previous
//
#include <hip/hip_runtime.h>
#include <hip/hip_bf16.h>

// Problem dims
#define BB 16
#define SS 512
#define IN_ 128
#define DD 512
#define HH 512
#define DA 30
#define RR 10
#define G3 1536   // 3*H

// ---- ws layout (bytes) ----
constexpr size_t OFF_H    = 0;                        // tagged h ring u32[2][16][512]: 65,536
constexpr size_t OFF_DF   = 131072;                   // dtype flag: 256
constexpr size_t OFF_CX   = OFF_DF   + 256;           // canonical fp32 inputs
constexpr size_t OFF_CW0  = OFF_CX   + 4194304;
constexpr size_t OFF_CB0  = OFF_CW0  + 262144;
constexpr size_t OFF_CW1  = OFF_CB0  + 2048;
constexpr size_t OFF_CB1  = OFF_CW1  + 61440;
constexpr size_t OFF_CW2  = OFF_CB1  + 256;
constexpr size_t OFF_CB2  = OFF_CW2  + 2048;
constexpr size_t OFF_CWIH = OFF_CB2  + 256;
constexpr size_t OFF_CWHH = OFF_CWIH + 3145728;
constexpr size_t OFF_CBI  = OFF_CWHH + 3145728;
constexpr size_t OFF_CBH  = OFF_CBI  + 6144;
constexpr size_t OFF_WT   = OFF_CBH  + 6144;          // W_hh^T bf16 [1536][512]
constexpr size_t OFF_WIHT = OFF_WT   + 1572864;       // W_ih^T bf16 [1536][512]
constexpr size_t OFF_MM   = OFF_WIHT + 1572864;       // M bf16 [8192][512]
constexpr size_t OFF_BIG  = OFF_MM   + 8388608;
constexpr size_t OFF_M    = OFF_BIG;                  // m bf16 [8192][512]
constexpr size_t OFF_E    = OFF_BIG  + 8388608;       // e f32 [8192][10]
constexpr size_t OFF_INV  = OFF_E    + 327680;        // inv f32
constexpr size_t OFF_GI   = OFF_BIG;                  // gi aliases m/e/inv (dead after k_attn)
constexpr size_t NEED_GI32 = OFF_BIG + 50331648;      // gi fp32 path total

typedef __attribute__((ext_vector_type(8))) short bf16x8;
typedef __attribute__((ext_vector_type(4))) float f32x4;

__device__ __forceinline__ float bflo(unsigned int u) { return __uint_as_float(u << 16); }
__device__ __forceinline__ float bfhi(unsigned int u) { return __uint_as_float(u & 0xffff0000u); }
__device__ __forceinline__ float bf1(unsigned short u) { return __uint_as_float(((unsigned int)u) << 16); }

__device__ __forceinline__ float ldgi(const float* p) { return *p; }
__device__ __forceinline__ float ldgi(const __hip_bfloat16* p) { return __bfloat162float(*p); }
__device__ __forceinline__ void stgi(float* p, float v) { *p = v; }
__device__ __forceinline__ void stgi(__hip_bfloat16* p, float v) { *p = __float2bfloat16(v); }

// ---------------- K0a: detect input dtype. fp32 reinterpreted as bf16 -> ~45% huge/NaN. ----
__global__ __launch_bounds__(256) void k_detect(const unsigned short* __restrict__ xs,
                                                int* __restrict__ dflag) {
  const int tid = threadIdx.x;
  int bad = 0;
  for (int i = tid; i < 8192; i += 256) {
    const float v = bf1(xs[i]);
    if (!(fabsf(v) < 1.0e3f)) bad++;   // NaN also counts
  }
  __shared__ int s;
  if (tid == 0) s = 0;
  __syncthreads();
  atomicAdd(&s, bad);
  __syncthreads();
  if (tid == 0) dflag[0] = (s > 16) ? 1 : 0;   // 1 = fp32 buffers, 0 = bf16 buffers
}

// ---------------- K0b: canonicalize all inputs to fp32 ----------------
struct CvtArgs { const void* src[11]; float* dst[11]; int n[11]; };
__global__ __launch_bounds__(256) void k_cvt(CvtArgs a, const int* __restrict__ dflag) {
  const int ai = blockIdx.y;
  const int n = a.n[ai];
  const int stride = gridDim.x * blockDim.x;
  const int f32 = dflag[0];
  float* dst = a.dst[ai];
  if (f32) {
    const float* src = (const float*)a.src[ai];
    for (int i = blockIdx.x * blockDim.x + threadIdx.x; i < n; i += stride) dst[i] = src[i];
  } else {
    const unsigned short* src = (const unsigned short*)a.src[ai];
    for (int i = blockIdx.x * blockDim.x + threadIdx.x; i < n; i += stride) dst[i] = bf1(src[i]);
  }
}

// ---------------- K1: transpose 512x1536 f32 -> 1536x512 bf16 (used for W_hh and W_ih) ----
__global__ __launch_bounds__(1024) void k_transpose(const float* __restrict__ W,
                                                    __hip_bfloat16* __restrict__ WT) {
  __shared__ float tile[32][33];
  const int c0 = blockIdx.x * 32;   // col in [0,1536)
  const int k0 = blockIdx.y * 32;   // row in [0,512)
  tile[threadIdx.y][threadIdx.x] = W[(k0 + threadIdx.y) * G3 + c0 + threadIdx.x];
  __syncthreads();
  WT[(c0 + threadIdx.y) * DD + k0 + threadIdx.x] = __float2bfloat16(tile[threadIdx.x][threadIdx.y]);
}

// ---------------- K2: per-row fused encoder: m=relu(x@W0+b0); e=exp(tanh(m@W1+b1)@W2+b2) ----
__global__ __launch_bounds__(256) void k_encoder(const float* __restrict__ x,
    const float* __restrict__ W0, const float* __restrict__ b0,
    const float* __restrict__ W1, const float* __restrict__ b1,
    const float* __restrict__ W2, const float* __restrict__ b2,
    __hip_bfloat16* __restrict__ mo, float* __restrict__ e) {
  const int row = blockIdx.x;        // b*512+s
  const int tid = threadIdx.x;       // 256
  __shared__ float xs[IN_];
  __shared__ float ms[DD];
  __shared__ float as[DA];
  __shared__ float part[8][32];
  if (tid < IN_) xs[tid] = x[row * IN_ + tid];
  __syncthreads();
  const int d0 = tid * 2;
  float acc0 = 0.f, acc1 = 0.f;
  #pragma unroll 8
  for (int k = 0; k < IN_; k++) {
    const float xv = xs[k];
    const float2 w = *(const float2*)(W0 + k * DD + d0);
    acc0 = fmaf(xv, w.x, acc0);
    acc1 = fmaf(xv, w.y, acc1);
  }
  const float m0 = fmaxf(acc0 + b0[d0], 0.f);
  const float m1 = fmaxf(acc1 + b0[d0 + 1], 0.f);
  ms[d0] = m0; ms[d0 + 1] = m1;
  mo[row * DD + d0] = __float2bfloat16(m0);
  mo[row * DD + d0 + 1] = __float2bfloat16(m1);
  __syncthreads();
  // m@W1: seg-split over k — all 256 threads active (a2<30 lanes idle only)
  const int a2 = tid & 31, seg = tid >> 5;
  float p = 0.f;
  if (a2 < DA) {
    const int kb = seg * 64;
    #pragma unroll 8
    for (int k = 0; k < 64; k++) p = fmaf(ms[kb + k], W1[(kb + k) * DA + a2], p);
  }
  part[seg][a2] = p;
  __syncthreads();
  if (tid < DA) {
    float a = b1[tid];
    #pragma unroll
    for (int s = 0; s < 8; s++) a += part[s][tid];
    as[tid] = tanhf(a);
  }
  __syncthreads();
  if (tid < RR) {
    float s = b2[tid];
    #pragma unroll
    for (int j = 0; j < DA; j++) s = fmaf(as[j], W2[j * RR + tid], s);
    e[row * RR + tid] = __expf(s);
  }
}

// ---------------- K3: per-(b,r) prefix scan -> inv[b,k,r] = 1/cumsum_k e ----------------
__global__ __launch_bounds__(64) void k_scan(const float* __restrict__ e, float* __restrict__ inv) {
  const int b = blockIdx.x / RR, r = blockIdx.x % RR;
  const int lane = threadIdx.x;  // 64
  float v[8];
  float sum = 0.f;
  #pragma unroll
  for (int i = 0; i < 8; i++) { v[i] = e[(b * SS + lane * 8 + i) * RR + r]; sum += v[i]; }
  float inc = sum;
  #pragma unroll
  for (int off = 1; off < 64; off <<= 1) {
    float n = __shfl_up(inc, off);
    if (lane >= off) inc += n;
  }
  float c = inc - sum;  // exclusive prefix
  #pragma unroll
  for (int i = 0; i < 8; i++) { c += v[i]; inv[(b * SS + lane * 8 + i) * RR + r] = 1.0f / c; }
}

// ---------------- K4: attention as streaming scan: M[t,d] = (1/R) sum_r cums(e*m)*inv ----
__global__ __launch_bounds__(128) void k_attn(const __hip_bfloat16* __restrict__ m,
    const float* __restrict__ e, const float* __restrict__ inv, __hip_bfloat16* __restrict__ M) {
  const int b = blockIdx.y;
  const int d = blockIdx.x * 128 + threadIdx.x;
  __shared__ float es[SS * RR];
  __shared__ float is[SS * RR];
  for (int i = threadIdx.x; i < SS * RR; i += 128) {
    es[i] = e[b * SS * RR + i];
    is[i] = inv[b * SS * RR + i];
  }
  __syncthreads();
  float num[RR];
  #pragma unroll
  for (int r = 0; r < RR; r++) num[r] = 0.f;
  const __hip_bfloat16* mb = m + (size_t)b * SS * DD + d;
  __hip_bfloat16* Mb = M + (size_t)b * SS * DD + d;
  for (int k = 0; k < SS; k++) {
    const float mv = __bfloat162float(mb[(size_t)k * DD]);
    float acc = 0.f;
    #pragma unroll
    for (int r = 0; r < RR; r++) {
      num[r] = fmaf(es[k * RR + r], mv, num[r]);
      acc = fmaf(num[r], is[k * RR + r], acc);
    }
    Mb[(size_t)k * DD] = __float2bfloat16(acc * (1.0f / RR));
  }
}

// ---------------- K5: gi = Mm @ W_ih + b_i via MFMA 16x16x32 bf16 ----------------
// A = Mm [8192][512] bf16 row-major; Bt = W_ih^T [1536][512] bf16 row-major.
// Tile 128x128, 4 waves (2x2 of 64x64), BK=32. Fragments: A[m=lane&15][k=quad*8+j],
// B[k][n]: n=lane&15, same k-octet. C/D: col=lane&15, row=quad*4+reg (m89-verified).
template<typename GT>
__global__ __launch_bounds__(256) void k_gemm_mfma(const __hip_bfloat16* __restrict__ A,
    const __hip_bfloat16* __restrict__ Bt, const float* __restrict__ bias,
    GT* __restrict__ C) {
  __shared__ short As[128 * 40];   // 128 rows x 32 k, stride 40 (bank de-phase)
  __shared__ short Bs[128 * 40];
  const int tid = threadIdx.x;
  const int bn = blockIdx.x * 128, bm = blockIdx.y * 128;
  const int lane = tid & 63, w = tid >> 6;
  const int wm = (w >> 1) * 64, wn = (w & 1) * 64;
  const int l15 = lane & 15, quad = lane >> 4;
  const int srow = tid >> 1, shalf = tid & 1;    // staging: row, 16-bf16 half of the 32-chunk
  f32x4 acc[4][4];
  #pragma unroll
  for (int i = 0; i < 4; i++)
    #pragma unroll
    for (int j = 0; j < 4; j++) acc[i][j] = (f32x4){0.f, 0.f, 0.f, 0.f};
  const uint4* Ag = (const uint4*)(A + (size_t)(bm + srow) * DD);
  const uint4* Bg = (const uint4*)(Bt + (size_t)(bn + srow) * DD);
  short* Asd = &As[srow * 40 + shalf * 16];
  short* Bsd = &Bs[srow * 40 + shalf * 16];
  for (int kc = 0; kc < 16; kc++) {
    const int gi4 = kc * 4 + shalf * 2;
    const uint4 a0 = Ag[gi4], a1 = Ag[gi4 + 1];
    const uint4 b0 = Bg[gi4], b1 = Bg[gi4 + 1];
    *(uint4*)&Asd[0] = a0; *(uint4*)&Asd[8] = a1;
    *(uint4*)&Bsd[0] = b0; *(uint4*)&Bsd[8] = b1;
    __syncthreads();
    bf16x8 af[4], bf[4];
    #pragma unroll
    for (int tt = 0; tt < 4; tt++) {
      af[tt] = *(const bf16x8*)&As[(wm + tt * 16 + l15) * 40 + quad * 8];
      bf[tt] = *(const bf16x8*)&Bs[(wn + tt * 16 + l15) * 40 + quad * 8];
    }
    #pragma unroll
    for (int tm = 0; tm < 4; tm++)
      #pragma unroll
      for (int tn = 0; tn < 4; tn++)
        acc[tm][tn] = __builtin_amdgcn_mfma_f32_16x16x32_bf16(af[tm], bf[tn], acc[tm][tn], 0, 0, 0);
    __syncthreads();
  }
  #pragma unroll
  for (int tn = 0; tn < 4; tn++) {
    const int col = bn + wn + tn * 16 + l15;
    const float bv = bias[col];
    #pragma unroll
    for (int tm = 0; tm < 4; tm++) {
      const int row = bm + wm + tm * 16 + quad * 4;
      #pragma unroll
      for (int i = 0; i < 4; i++)
        stgi(C + (size_t)(row + i) * G3 + col, acc[tm][tn][i] + bv);
    }
  }
}

// ---------------- K6: persistent GRU, u32 mantissa-tagged sync (tear-proof) ----------------
// 32 j-slices x 16 batches = 512 blocks, 192 thr. W quarter-rows in VGPRs (16 uint4/thr).
// h exchanged as a SINGLE u32: fp32 bits with low 2 mantissa bits = step tag (t&3).
// Single-dword access cannot tear (unlike u64 tag|value pairs). Skew bound: reader at step
// t implies every block finished step t-2, so a parity buffer holds only tags t or t-2 —
// they differ in tag bit 1, always distinguishable. Value perturbation 2^-22 rel (negligible).
template<typename GT>
__global__ __launch_bounds__(192) void k_gru(const __hip_bfloat16* __restrict__ WT,
    const GT* __restrict__ gi, const float* __restrict__ bh,
    unsigned int* __restrict__ hslots, void* __restrict__ outv,
    const int* __restrict__ dflag) {
  const int b = blockIdx.y, g = blockIdx.x, tid = threadIdx.x; // g<32
  const int f32o = dflag[0];
  const int c = tid >> 2, q = tid & 3;           // row c<48, k-quarter q<4
  const int col = ((c >> 4) << 9) + (g << 4) + (c & 15);
  __shared__ __align__(16) float hs4[4 * 132];   // h in 4 padded quarters
  __shared__ float ghs[48];
  __shared__ float gis[48];
  // W quarter-row resident in registers: 128 bf16 = 16 uint4 (64 VGPRs)
  uint4 wr[16];
  {
    const uint4* wp = (const uint4*)(WT + (size_t)col * HH + q * 128);
    #pragma unroll
    for (int i = 0; i < 16; i++) wr[i] = wp[i];
  }
  const float bias_c = bh[col];
  // wave-2 gi prefetch lane mapping (tid 128..175 <-> slot 0..47); waves 0-1 poll h.
  const int pslot = tid - 128;
  const bool pf = (pslot >= 0 && pslot < 48);
  const int gcol = pf ? (((pslot >> 4) << 9) + (g << 4) + (pslot & 15)) : 0;
  unsigned int* s0 = hslots + b * HH;
  unsigned int* s1 = hslots + BB * HH + b * HH;
  const GT* gib = gi + (size_t)b * SS * G3;
  float gpre = pf ? ldgi(gib + gcol) : 0.f;

  for (int t = 0; t < SS; t++) {
    unsigned int* cur = (t & 1) ? s1 : s0;
    unsigned int* nxt = (t & 1) ? s0 : s1;
    // poll+stage h_t: 128 threads x 4 slots; parallel re-poll of all pending slots
    if (tid < 128) {
      unsigned done = 0;
      unsigned v[4];
      const unsigned want = ((unsigned)t) & 3u;
      while (done != 0xFu) {
        #pragma unroll
        for (int u = 0; u < 4; u++)
          if (!(done & (1u << u)))
            v[u] = __hip_atomic_load(cur + tid + u * 128, __ATOMIC_RELAXED,
                                     __HIP_MEMORY_SCOPE_AGENT);
        #pragma unroll
        for (int u = 0; u < 4; u++)
          if (!(done & (1u << u)) && (v[u] & 3u) == want) {
            hs4[u * 132 + tid] = __uint_as_float(v[u]);
            done |= 1u << u;
          }
      }
    }
    if (pf) gis[pslot] = gpre;
    __syncthreads();                                    // #1
    if (pf && t + 1 < SS) gpre = ldgi(gib + (size_t)(t + 1) * G3 + gcol);  // overlap dot
    // dot: row col, k in [q*128, q*128+128)
    float a0 = 0.f, a1 = 0.f, a2 = 0.f, a3 = 0.f;
    const float4* hp = (const float4*)&hs4[q * 132];
    #pragma unroll
    for (int i = 0; i < 16; i++) {
      const uint4 w = wr[i];
      const float4 ha = hp[2 * i];
      const float4 hb = hp[2 * i + 1];
      a0 = fmaf(ha.x, bflo(w.x), a0); a1 = fmaf(ha.y, bfhi(w.x), a1);
      a2 = fmaf(ha.z, bflo(w.y), a2); a3 = fmaf(ha.w, bfhi(w.y), a3);
      a0 = fmaf(hb.x, bflo(w.z), a0); a1 = fmaf(hb.y, bfhi(w.z), a1);
      a2 = fmaf(hb.z, bflo(w.w), a2); a3 = fmaf(hb.w, bfhi(w.w), a3);
    }
    float acc = (a0 + a1) + (a2 + a3);
    acc += __shfl_xor(acc, 1);   // reduce across q (lane bits 0..1)
    acc += __shfl_xor(acc, 2);
    if (q == 0) ghs[c] = acc + bias_c;
    __syncthreads();                                    // #2
    if (tid < 16) {
      const float ghr = ghs[tid], ghz = ghs[16 + tid], ghn = ghs[32 + tid];
      const float gir = gis[tid], giz = gis[16 + tid], gin = gis[32 + tid];
      const float r = 1.f / (1.f + __expf(-(gir + ghr)));
      const float z = 1.f / (1.f + __expf(-(giz + ghz)));
      const float nx = gin + r * ghn;
      const float n = 1.f - 2.f / (__expf(2.f * nx) + 1.f);   // tanh
      const int j = (g << 4) + tid;
      const float hprev = hs4[(j >> 7) * 132 + (j & 127)];
      const float hnew = n + z * (hprev - n);
      const unsigned pk = (__float_as_uint(hnew) & ~3u) | (((unsigned)(t + 1)) & 3u);
      __hip_atomic_store(nxt + j, pk, __ATOMIC_RELAXED, __HIP_MEMORY_SCOPE_AGENT);
      const size_t oi = ((size_t)b * SS + t) * HH + j;
      if (f32o) ((float*)outv)[oi] = hnew;
      else ((__hip_bfloat16*)outv)[oi] = __float2bfloat16(hnew);
    }
    __syncthreads();                                    // #3 (hs4 WAR before next stage)
  }
}

extern "C" void kernel_launch(void* const* d_in, const int* in_sizes, int n_in,
                              void* d_out, int out_size, void* d_ws, size_t ws_size,
                              hipStream_t stream) {
  char* wsb = (char*)d_ws;
  unsigned int* hslots = (unsigned int*)(wsb + OFF_H);
  int* dflag  = (int*)(wsb + OFF_DF);
  float* cx   = (float*)(wsb + OFF_CX);
  float* cW0  = (float*)(wsb + OFF_CW0);
  float* cb0  = (float*)(wsb + OFF_CB0);
  float* cW1  = (float*)(wsb + OFF_CW1);
  float* cb1  = (float*)(wsb + OFF_CB1);
  float* cW2  = (float*)(wsb + OFF_CW2);
  float* cb2  = (float*)(wsb + OFF_CB2);
  float* cWih = (float*)(wsb + OFF_CWIH);
  float* cWhh = (float*)(wsb + OFF_CWHH);
  float* cbi  = (float*)(wsb + OFF_CBI);
  float* cbh  = (float*)(wsb + OFF_CBH);
  __hip_bfloat16* WT   = (__hip_bfloat16*)(wsb + OFF_WT);
  __hip_bfloat16* WihT = (__hip_bfloat16*)(wsb + OFF_WIHT);
  __hip_bfloat16* Mm   = (__hip_bfloat16*)(wsb + OFF_MM);
  __hip_bfloat16* m    = (__hip_bfloat16*)(wsb + OFF_M);
  float* e   = (float*)(wsb + OFF_E);
  float* inv = (float*)(wsb + OFF_INV);
  void* gip  = (void*)(wsb + OFF_GI);
  const bool gi32 = (ws_size >= NEED_GI32);   // constant across calls -> same work every call

  // zero tagged h ring (bits 0 == h=0.0 with tag 0). ws is poisoned 0xAA before every call.
  hipMemsetAsync(wsb, 0, 65536, stream);

  k_detect<<<1, 256, 0, stream>>>((const unsigned short*)d_in[0], dflag);

  CvtArgs ca;
  float* dsts[11] = {cx, cW0, cb0, cW1, cb1, cW2, cb2, cWih, cWhh, cbi, cbh};
  const int ns[11] = {BB * SS * IN_, IN_ * DD, DD, DD * DA, DA, DA * RR, RR,
                      DD * G3, HH * G3, G3, G3};
  for (int i = 0; i < 11; i++) { ca.src[i] = d_in[i]; ca.dst[i] = dsts[i]; ca.n[i] = ns[i]; }
  k_cvt<<<dim3(128, 11), 256, 0, stream>>>(ca, dflag);

  k_transpose<<<dim3(G3 / 32, DD / 32), dim3(32, 32), 0, stream>>>(cWhh, WT);
  k_transpose<<<dim3(G3 / 32, DD / 32), dim3(32, 32), 0, stream>>>(cWih, WihT);
  k_encoder<<<BB * SS, 256, 0, stream>>>(cx, cW0, cb0, cW1, cb1, cW2, cb2, m, e);
  k_scan<<<BB * RR, 64, 0, stream>>>(e, inv);
  k_attn<<<dim3(4, BB), 128, 0, stream>>>(m, e, inv, Mm);
  if (gi32) {
    k_gemm_mfma<float><<<dim3(G3 / 128, (BB * SS) / 128), 256, 0, stream>>>(Mm, WihT, cbi, (float*)gip);
    k_gru<float><<<dim3(32, BB), 192, 0, stream>>>(WT, (const float*)gip, cbh, hslots, d_out, dflag);
  } else {
    k_gemm_mfma<__hip_bfloat16><<<dim3(G3 / 128, (BB * SS) / 128), 256, 0, stream>>>(Mm, WihT, cbi, (__hip_bfloat16*)gip);
    k_gru<__hip_bfloat16><<<dim3(32, BB), 192, 0, stream>>>(WT, (const __hip_bfloat16*)gip, cbh, hslots, d_out, dflag);
  }
}

// Round 8
// 1336.763 us; speedup vs baseline: 3.6606x; 1.1341x over previous
//
#include <hip/hip_runtime.h>
#include <hip/hip_bf16.h>

// Problem dims
#define BB 16
#define SS 512
#define IN_ 128
#define DD 512
#define HH 512
#define DA 30
#define RR 10
#define G3 1536   // 3*H

// ---- ws layout (bytes) ----
constexpr size_t OFF_H    = 0;                        // tagged h ring u32[2][16][512]: 65,536
constexpr size_t OFF_DF   = 131072;                   // dtype flag: 256
constexpr size_t OFF_CX   = OFF_DF   + 256;           // canonical fp32 inputs
constexpr size_t OFF_CW0  = OFF_CX   + 4194304;
constexpr size_t OFF_CB0  = OFF_CW0  + 262144;
constexpr size_t OFF_CW1  = OFF_CB0  + 2048;
constexpr size_t OFF_CB1  = OFF_CW1  + 61440;
constexpr size_t OFF_CW2  = OFF_CB1  + 256;
constexpr size_t OFF_CB2  = OFF_CW2  + 2048;
constexpr size_t OFF_CWIH = OFF_CB2  + 256;
constexpr size_t OFF_CWHH = OFF_CWIH + 3145728;
constexpr size_t OFF_CBI  = OFF_CWHH + 3145728;
constexpr size_t OFF_CBH  = OFF_CBI  + 6144;
constexpr size_t OFF_WT   = OFF_CBH  + 6144;          // W_hh^T bf16 [1536][512]
constexpr size_t OFF_WIHT = OFF_WT   + 1572864;       // W_ih^T bf16 [1536][512]
constexpr size_t OFF_MM   = OFF_WIHT + 1572864;       // M bf16 [8192][512]
constexpr size_t OFF_BIG  = OFF_MM   + 8388608;
constexpr size_t OFF_M    = OFF_BIG;                  // m bf16 [8192][512]
constexpr size_t OFF_E    = OFF_BIG  + 8388608;       // e f32 [8192][10]
constexpr size_t OFF_INV  = OFF_E    + 327680;        // inv f32
constexpr size_t OFF_GI   = OFF_BIG;                  // gi aliases m/e/inv (dead after k_attn)
constexpr size_t NEED_GI32 = OFF_BIG + 50331648;      // gi fp32 path total

typedef __attribute__((ext_vector_type(8))) short bf16x8;
typedef __attribute__((ext_vector_type(4))) float f32x4;

__device__ __forceinline__ float bflo(unsigned int u) { return __uint_as_float(u << 16); }
__device__ __forceinline__ float bfhi(unsigned int u) { return __uint_as_float(u & 0xffff0000u); }
__device__ __forceinline__ float bf1(unsigned short u) { return __uint_as_float(((unsigned int)u) << 16); }

__device__ __forceinline__ float ldgi(const float* p) { return *p; }
__device__ __forceinline__ float ldgi(const __hip_bfloat16* p) { return __bfloat162float(*p); }
__device__ __forceinline__ void stgi(float* p, float v) { *p = v; }
__device__ __forceinline__ void stgi(__hip_bfloat16* p, float v) { *p = __float2bfloat16(v); }

// ---------------- K0a: detect input dtype. fp32 reinterpreted as bf16 -> ~45% huge/NaN. ----
__global__ __launch_bounds__(256) void k_detect(const unsigned short* __restrict__ xs,
                                                int* __restrict__ dflag) {
  const int tid = threadIdx.x;
  int bad = 0;
  for (int i = tid; i < 8192; i += 256) {
    const float v = bf1(xs[i]);
    if (!(fabsf(v) < 1.0e3f)) bad++;   // NaN also counts
  }
  __shared__ int s;
  if (tid == 0) s = 0;
  __syncthreads();
  atomicAdd(&s, bad);
  __syncthreads();
  if (tid == 0) dflag[0] = (s > 16) ? 1 : 0;   // 1 = fp32 buffers, 0 = bf16 buffers
}

// ---------------- K0b: canonicalize all inputs to fp32 ----------------
struct CvtArgs { const void* src[11]; float* dst[11]; int n[11]; };
__global__ __launch_bounds__(256) void k_cvt(CvtArgs a, const int* __restrict__ dflag) {
  const int ai = blockIdx.y;
  const int n = a.n[ai];
  const int stride = gridDim.x * blockDim.x;
  const int f32 = dflag[0];
  float* dst = a.dst[ai];
  if (f32) {
    const float* src = (const float*)a.src[ai];
    for (int i = blockIdx.x * blockDim.x + threadIdx.x; i < n; i += stride) dst[i] = src[i];
  } else {
    const unsigned short* src = (const unsigned short*)a.src[ai];
    for (int i = blockIdx.x * blockDim.x + threadIdx.x; i < n; i += stride) dst[i] = bf1(src[i]);
  }
}

// ---------------- K1: transpose 512x1536 f32 -> 1536x512 bf16 (used for W_hh and W_ih) ----
__global__ __launch_bounds__(1024) void k_transpose(const float* __restrict__ W,
                                                    __hip_bfloat16* __restrict__ WT) {
  __shared__ float tile[32][33];
  const int c0 = blockIdx.x * 32;   // col in [0,1536)
  const int k0 = blockIdx.y * 32;   // row in [0,512)
  tile[threadIdx.y][threadIdx.x] = W[(k0 + threadIdx.y) * G3 + c0 + threadIdx.x];
  __syncthreads();
  WT[(c0 + threadIdx.y) * DD + k0 + threadIdx.x] = __float2bfloat16(tile[threadIdx.x][threadIdx.y]);
}

// ---------------- K2: per-row fused encoder: m=relu(x@W0+b0); e=exp(tanh(m@W1+b1)@W2+b2) ----
__global__ __launch_bounds__(256) void k_encoder(const float* __restrict__ x,
    const float* __restrict__ W0, const float* __restrict__ b0,
    const float* __restrict__ W1, const float* __restrict__ b1,
    const float* __restrict__ W2, const float* __restrict__ b2,
    __hip_bfloat16* __restrict__ mo, float* __restrict__ e) {
  const int row = blockIdx.x;        // b*512+s
  const int tid = threadIdx.x;       // 256
  __shared__ float xs[IN_];
  __shared__ float ms[DD];
  __shared__ float as[DA];
  __shared__ float part[8][32];
  if (tid < IN_) xs[tid] = x[row * IN_ + tid];
  __syncthreads();
  const int d0 = tid * 2;
  float acc0 = 0.f, acc1 = 0.f;
  #pragma unroll 8
  for (int k = 0; k < IN_; k++) {
    const float xv = xs[k];
    const float2 w = *(const float2*)(W0 + k * DD + d0);
    acc0 = fmaf(xv, w.x, acc0);
    acc1 = fmaf(xv, w.y, acc1);
  }
  const float m0 = fmaxf(acc0 + b0[d0], 0.f);
  const float m1 = fmaxf(acc1 + b0[d0 + 1], 0.f);
  ms[d0] = m0; ms[d0 + 1] = m1;
  mo[row * DD + d0] = __float2bfloat16(m0);
  mo[row * DD + d0 + 1] = __float2bfloat16(m1);
  __syncthreads();
  // m@W1: seg-split over k — all 256 threads active (a2<30 lanes idle only)
  const int a2 = tid & 31, seg = tid >> 5;
  float p = 0.f;
  if (a2 < DA) {
    const int kb = seg * 64;
    #pragma unroll 8
    for (int k = 0; k < 64; k++) p = fmaf(ms[kb + k], W1[(kb + k) * DA + a2], p);
  }
  part[seg][a2] = p;
  __syncthreads();
  if (tid < DA) {
    float a = b1[tid];
    #pragma unroll
    for (int s = 0; s < 8; s++) a += part[s][tid];
    as[tid] = tanhf(a);
  }
  __syncthreads();
  if (tid < RR) {
    float s = b2[tid];
    #pragma unroll
    for (int j = 0; j < DA; j++) s = fmaf(as[j], W2[j * RR + tid], s);
    e[row * RR + tid] = __expf(s);
  }
}

// ---------------- K3: per-(b,r) prefix scan -> inv[b,k,r] = 1/cumsum_k e ----------------
__global__ __launch_bounds__(64) void k_scan(const float* __restrict__ e, float* __restrict__ inv) {
  const int b = blockIdx.x / RR, r = blockIdx.x % RR;
  const int lane = threadIdx.x;  // 64
  float v[8];
  float sum = 0.f;
  #pragma unroll
  for (int i = 0; i < 8; i++) { v[i] = e[(b * SS + lane * 8 + i) * RR + r]; sum += v[i]; }
  float inc = sum;
  #pragma unroll
  for (int off = 1; off < 64; off <<= 1) {
    float n = __shfl_up(inc, off);
    if (lane >= off) inc += n;
  }
  float c = inc - sum;  // exclusive prefix
  #pragma unroll
  for (int i = 0; i < 8; i++) { c += v[i]; inv[(b * SS + lane * 8 + i) * RR + r] = 1.0f / c; }
}

// ---------------- K4: attention as streaming scan: M[t,d] = (1/R) sum_r cums(e*m)*inv ----
__global__ __launch_bounds__(128) void k_attn(const __hip_bfloat16* __restrict__ m,
    const float* __restrict__ e, const float* __restrict__ inv, __hip_bfloat16* __restrict__ M) {
  const int b = blockIdx.y;
  const int d = blockIdx.x * 128 + threadIdx.x;
  __shared__ float es[SS * RR];
  __shared__ float is[SS * RR];
  for (int i = threadIdx.x; i < SS * RR; i += 128) {
    es[i] = e[b * SS * RR + i];
    is[i] = inv[b * SS * RR + i];
  }
  __syncthreads();
  float num[RR];
  #pragma unroll
  for (int r = 0; r < RR; r++) num[r] = 0.f;
  const __hip_bfloat16* mb = m + (size_t)b * SS * DD + d;
  __hip_bfloat16* Mb = M + (size_t)b * SS * DD + d;
  for (int k = 0; k < SS; k++) {
    const float mv = __bfloat162float(mb[(size_t)k * DD]);
    float acc = 0.f;
    #pragma unroll
    for (int r = 0; r < RR; r++) {
      num[r] = fmaf(es[k * RR + r], mv, num[r]);
      acc = fmaf(num[r], is[k * RR + r], acc);
    }
    Mb[(size_t)k * DD] = __float2bfloat16(acc * (1.0f / RR));
  }
}

// ---------------- K5: gi = Mm @ W_ih + b_i via MFMA 16x16x32 bf16 ----------------
template<typename GT>
__global__ __launch_bounds__(256) void k_gemm_mfma(const __hip_bfloat16* __restrict__ A,
    const __hip_bfloat16* __restrict__ Bt, const float* __restrict__ bias,
    GT* __restrict__ C) {
  __shared__ short As[128 * 40];   // 128 rows x 32 k, stride 40 (bank de-phase)
  __shared__ short Bs[128 * 40];
  const int tid = threadIdx.x;
  const int bn = blockIdx.x * 128, bm = blockIdx.y * 128;
  const int lane = tid & 63, w = tid >> 6;
  const int wm = (w >> 1) * 64, wn = (w & 1) * 64;
  const int l15 = lane & 15, quad = lane >> 4;
  const int srow = tid >> 1, shalf = tid & 1;    // staging: row, 16-bf16 half of the 32-chunk
  f32x4 acc[4][4];
  #pragma unroll
  for (int i = 0; i < 4; i++)
    #pragma unroll
    for (int j = 0; j < 4; j++) acc[i][j] = (f32x4){0.f, 0.f, 0.f, 0.f};
  const uint4* Ag = (const uint4*)(A + (size_t)(bm + srow) * DD);
  const uint4* Bg = (const uint4*)(Bt + (size_t)(bn + srow) * DD);
  short* Asd = &As[srow * 40 + shalf * 16];
  short* Bsd = &Bs[srow * 40 + shalf * 16];
  for (int kc = 0; kc < 16; kc++) {
    const int gi4 = kc * 4 + shalf * 2;
    const uint4 a0 = Ag[gi4], a1 = Ag[gi4 + 1];
    const uint4 b0 = Bg[gi4], b1 = Bg[gi4 + 1];
    *(uint4*)&Asd[0] = a0; *(uint4*)&Asd[8] = a1;
    *(uint4*)&Bsd[0] = b0; *(uint4*)&Bsd[8] = b1;
    __syncthreads();
    bf16x8 af[4], bf[4];
    #pragma unroll
    for (int tt = 0; tt < 4; tt++) {
      af[tt] = *(const bf16x8*)&As[(wm + tt * 16 + l15) * 40 + quad * 8];
      bf[tt] = *(const bf16x8*)&Bs[(wn + tt * 16 + l15) * 40 + quad * 8];
    }
    #pragma unroll
    for (int tm = 0; tm < 4; tm++)
      #pragma unroll
      for (int tn = 0; tn < 4; tn++)
        acc[tm][tn] = __builtin_amdgcn_mfma_f32_16x16x32_bf16(af[tm], bf[tn], acc[tm][tn], 0, 0, 0);
    __syncthreads();
  }
  #pragma unroll
  for (int tn = 0; tn < 4; tn++) {
    const int col = bn + wn + tn * 16 + l15;
    const float bv = bias[col];
    #pragma unroll
    for (int tm = 0; tm < 4; tm++) {
      const int row = bm + wm + tm * 16 + quad * 4;
      #pragma unroll
      for (int i = 0; i < 4; i++)
        stgi(C + (size_t)(row + i) * G3 + col, acc[tm][tn][i] + bv);
    }
  }
}

// ---------------- K6 v4: persistent GRU — 16 blocks/batch, 1 block/CU, 2 barriers ------
// 256 blocks x 384 thr. Block = (batch b, j-slice g of 32 cols). XCD-affinity swizzle:
// lin = b%8 + 8*(g + 16*(b/8)) -> all 16 blocks of a batch on one XCD (heuristic only).
// W rows (96 x 512) in VGPRs: thread (c<96, q<4) holds 128 bf16 (16 uint4).
// h exchanged as u32 fp32-bits with 2-bit mantissa step-tag (tear-proof), parity-2 ring.
// Poll: tid<128, ONE dwordx4 sc0 sc1 per sweep (4 self-tagged dwords). hs4/gis parity
// double-buffered in LDS -> only 2 barriers/step. Gates on dedicated wave (tid 352..383);
// gi prefetch on tid 256..351 (disjoint waves from pollers -> independent vmcnt).
template<typename GT>
__global__ __launch_bounds__(384) void k_gru(const __hip_bfloat16* __restrict__ WT,
    const GT* __restrict__ gi, const float* __restrict__ bh,
    unsigned int* __restrict__ hslots, void* __restrict__ outv,
    const int* __restrict__ dflag) {
  const int lin = blockIdx.x, tid = threadIdx.x;
  const int xcd = lin & 7, within = lin >> 3;
  const int b = xcd + 8 * (within >> 4);
  const int g = within & 15;                     // j-slice: j in [g*32, g*32+32)
  const int f32o = dflag[0];
  const int c = tid >> 2, q = tid & 3;           // row c<96 (= gate*32+jj), k-quarter q<4
  const int col = ((c >> 5) << 9) + (g << 5) + (c & 31);
  __shared__ __align__(16) float hs4[2][4 * 132];   // parity x 4 padded quarters
  __shared__ float ghs[96];
  __shared__ float gis[2][96];
  // W quarter-row resident in registers: 128 bf16 = 16 uint4 (64 VGPRs)
  uint4 wr[16];
  {
    const uint4* wp = (const uint4*)(WT + (size_t)col * HH + q * 128);
    #pragma unroll
    for (int i = 0; i < 16; i++) wr[i] = wp[i];
  }
  const float bias_c = bh[col];
  // gi prefetch threads: tid in [256,352) <-> slot 0..95
  const int pslot = tid - 256;
  const bool pf = (pslot >= 0 && pslot < 96);
  const int gcol = pf ? (((pslot >> 5) << 9) + (g << 5) + (pslot & 31)) : 0;
  // gates threads: tid in [352,384) <-> jj 0..31
  const bool gt = (tid >= 352);
  const int jj = tid - 352;
  const int jg = (g << 5) + jj;
  unsigned int* s0 = hslots + b * HH;
  unsigned int* s1 = hslots + BB * HH + b * HH;
  const GT* gib = gi + (size_t)b * SS * G3;
  float gpre = pf ? ldgi(gib + gcol) : 0.f;

  for (int t = 0; t < SS; t++) {
    const int par = t & 1;
    unsigned int* cur = par ? s1 : s0;
    unsigned int* nxt = par ? s0 : s1;
    // poll+stage h_t: tid<128 polls one uint4 (slots 4tid..4tid+3, same quarter)
    if (tid < 128) {
      const unsigned want = ((unsigned)t) & 3u;
      const uint4* src = ((const uint4*)cur) + tid;
      uint4 v;
      for (;;) {
        asm volatile("global_load_dwordx4 %0, %1, off sc0 sc1\n\ts_waitcnt vmcnt(0)"
                     : "=v"(v) : "v"(src) : "memory");
        if ((v.x & 3u) == want && (v.y & 3u) == want &&
            (v.z & 3u) == want && (v.w & 3u) == want) break;
      }
      float* dq = &hs4[par][(tid >> 5) * 132 + ((tid * 4) & 127)];
      dq[0] = __uint_as_float(v.x); dq[1] = __uint_as_float(v.y);
      dq[2] = __uint_as_float(v.z); dq[3] = __uint_as_float(v.w);
    }
    if (pf) gis[par][pslot] = gpre;
    __syncthreads();                                    // #1 (stage -> dot)
    if (pf && t + 1 < SS) gpre = ldgi(gib + (size_t)(t + 1) * G3 + gcol);  // overlap dot
    // dot: row col, k in [q*128, q*128+128)
    float a0 = 0.f, a1 = 0.f, a2 = 0.f, a3 = 0.f;
    const float4* hp = (const float4*)&hs4[par][q * 132];
    #pragma unroll
    for (int i = 0; i < 16; i++) {
      const uint4 w = wr[i];
      const float4 ha = hp[2 * i];
      const float4 hb = hp[2 * i + 1];
      a0 = fmaf(ha.x, bflo(w.x), a0); a1 = fmaf(ha.y, bfhi(w.x), a1);
      a2 = fmaf(ha.z, bflo(w.y), a2); a3 = fmaf(ha.w, bfhi(w.y), a3);
      a0 = fmaf(hb.x, bflo(w.z), a0); a1 = fmaf(hb.y, bfhi(w.z), a1);
      a2 = fmaf(hb.z, bflo(w.w), a2); a3 = fmaf(hb.w, bfhi(w.w), a3);
    }
    float acc = (a0 + a1) + (a2 + a3);
    acc += __shfl_xor(acc, 1);   // reduce across q (lane bits 0..1)
    acc += __shfl_xor(acc, 2);
    if (q == 0) ghs[c] = acc + bias_c;
    __syncthreads();                                    // #2 (ghs/gis -> gates; hs4 WAR)
    if (gt) {
      const float ghr = ghs[jj], ghz = ghs[32 + jj], ghn = ghs[64 + jj];
      const float gir = gis[par][jj], giz = gis[par][32 + jj], gin = gis[par][64 + jj];
      const float r = 1.f / (1.f + __expf(-(gir + ghr)));
      const float z = 1.f / (1.f + __expf(-(giz + ghz)));
      const float nx = gin + r * ghn;
      const float n = 1.f - 2.f / (__expf(2.f * nx) + 1.f);   // tanh
      const float hprev = hs4[par][(jg >> 7) * 132 + (jg & 127)];
      const float hnew = n + z * (hprev - n);
      const unsigned pk = (__float_as_uint(hnew) & ~3u) | (((unsigned)(t + 1)) & 3u);
      __hip_atomic_store(nxt + jg, pk, __ATOMIC_RELAXED, __HIP_MEMORY_SCOPE_AGENT);
      const size_t oi = ((size_t)b * SS + t) * HH + jg;
      if (f32o) ((float*)outv)[oi] = hnew;
      else ((__hip_bfloat16*)outv)[oi] = __float2bfloat16(hnew);
    }
    // no barrier #3: hs4/gis are parity double-buffered; ghs WAR is fenced by barrier #1
  }
}

extern "C" void kernel_launch(void* const* d_in, const int* in_sizes, int n_in,
                              void* d_out, int out_size, void* d_ws, size_t ws_size,
                              hipStream_t stream) {
  char* wsb = (char*)d_ws;
  unsigned int* hslots = (unsigned int*)(wsb + OFF_H);
  int* dflag  = (int*)(wsb + OFF_DF);
  float* cx   = (float*)(wsb + OFF_CX);
  float* cW0  = (float*)(wsb + OFF_CW0);
  float* cb0  = (float*)(wsb + OFF_CB0);
  float* cW1  = (float*)(wsb + OFF_CW1);
  float* cb1  = (float*)(wsb + OFF_CB1);
  float* cW2  = (float*)(wsb + OFF_CW2);
  float* cb2  = (float*)(wsb + OFF_CB2);
  float* cWih = (float*)(wsb + OFF_CWIH);
  float* cWhh = (float*)(wsb + OFF_CWHH);
  float* cbi  = (float*)(wsb + OFF_CBI);
  float* cbh  = (float*)(wsb + OFF_CBH);
  __hip_bfloat16* WT   = (__hip_bfloat16*)(wsb + OFF_WT);
  __hip_bfloat16* WihT = (__hip_bfloat16*)(wsb + OFF_WIHT);
  __hip_bfloat16* Mm   = (__hip_bfloat16*)(wsb + OFF_MM);
  __hip_bfloat16* m    = (__hip_bfloat16*)(wsb + OFF_M);
  float* e   = (float*)(wsb + OFF_E);
  float* inv = (float*)(wsb + OFF_INV);
  void* gip  = (void*)(wsb + OFF_GI);
  const bool gi32 = (ws_size >= NEED_GI32);   // constant across calls -> same work every call

  // zero tagged h ring (bits 0 == h=0.0 with tag 0). ws is poisoned 0xAA before every call.
  hipMemsetAsync(wsb, 0, 65536, stream);

  k_detect<<<1, 256, 0, stream>>>((const unsigned short*)d_in[0], dflag);

  CvtArgs ca;
  float* dsts[11] = {cx, cW0, cb0, cW1, cb1, cW2, cb2, cWih, cWhh, cbi, cbh};
  const int ns[11] = {BB * SS * IN_, IN_ * DD, DD, DD * DA, DA, DA * RR, RR,
                      DD * G3, HH * G3, G3, G3};
  for (int i = 0; i < 11; i++) { ca.src[i] = d_in[i]; ca.dst[i] = dsts[i]; ca.n[i] = ns[i]; }
  k_cvt<<<dim3(128, 11), 256, 0, stream>>>(ca, dflag);

  k_transpose<<<dim3(G3 / 32, DD / 32), dim3(32, 32), 0, stream>>>(cWhh, WT);
  k_transpose<<<dim3(G3 / 32, DD / 32), dim3(32, 32), 0, stream>>>(cWih, WihT);
  k_encoder<<<BB * SS, 256, 0, stream>>>(cx, cW0, cb0, cW1, cb1, cW2, cb2, m, e);
  k_scan<<<BB * RR, 64, 0, stream>>>(e, inv);
  k_attn<<<dim3(4, BB), 128, 0, stream>>>(m, e, inv, Mm);
  if (gi32) {
    k_gemm_mfma<float><<<dim3(G3 / 128, (BB * SS) / 128), 256, 0, stream>>>(Mm, WihT, cbi, (float*)gip);
    k_gru<float><<<256, 384, 0, stream>>>(WT, (const float*)gip, cbh, hslots, d_out, dflag);
  } else {
    k_gemm_mfma<__hip_bfloat16><<<dim3(G3 / 128, (BB * SS) / 128), 256, 0, stream>>>(Mm, WihT, cbi, (__hip_bfloat16*)gip);
    k_gru<__hip_bfloat16><<<256, 384, 0, stream>>>(WT, (const __hip_bfloat16*)gip, cbh, hslots, d_out, dflag);
  }
}